// Round 5
// baseline (293.157 us; speedup 1.0000x reference)
//
#include <hip/hip_runtime.h>
#include <cstdint>
#include <cstddef>

typedef __bf16 bf16x8 __attribute__((ext_vector_type(8)));
typedef float f32x4 __attribute__((ext_vector_type(4)));
typedef float f32x16 __attribute__((ext_vector_type(16)));
typedef unsigned short ushort8 __attribute__((ext_vector_type(8)));
typedef unsigned u32x2 __attribute__((ext_vector_type(2)));
typedef float f4 __attribute__((ext_vector_type(4)));

__device__ __forceinline__ unsigned short f2bf(float f) {
    __bf16 b = (__bf16)f;
    return *(unsigned short*)&b;
}
__device__ __forceinline__ unsigned pk2bf(float a, float b) {
    __bf16 x = (__bf16)a, y = (__bf16)b;
    unsigned short ux = *(unsigned short*)&x, uy = *(unsigned short*)&y;
    return (unsigned)ux | ((unsigned)uy << 16);
}
__device__ __forceinline__ float bf2f(unsigned short u) {
    union { unsigned u; float f; } v; v.u = ((unsigned)u) << 16; return v.f;
}

#if __has_builtin(__builtin_amdgcn_exp2f)
#define EXP2(x) __builtin_amdgcn_exp2f(x)
#else
#define EXP2(x) exp2f(x)
#endif

// exchange high 32 lanes of x with low 32 lanes of y (v_permlane32_swap_b32)
__device__ __forceinline__ void pl32swap(unsigned& x, unsigned& y) {
#if __has_builtin(__builtin_amdgcn_permlane32_swap)
    auto r = __builtin_amdgcn_permlane32_swap(x, y, false, false);
    x = r[0]; y = r[1];
#else
    unsigned xs = (unsigned)__shfl_xor((int)x, 32, 64);
    unsigned ys = (unsigned)__shfl_xor((int)y, 32, 64);
    bool lo = ((threadIdx.x & 63) < 32);
    unsigned nx = lo ? x : ys;
    unsigned ny = lo ? xs : y;
    x = nx; y = ny;
#endif
}

// ONLY the offset=0 form: the builtin's imm-offset field semantics on the
// LDS-DMA path are unverified (round-4 NaN). Explicit pointers instead.
#define GLL(g, l) __builtin_amdgcn_global_load_lds( \
    (__attribute__((address_space(1))) void*)(g), \
    (__attribute__((address_space(3))) void*)(l), 16, 0, 0)

#define CS 0.18033688011112042f   /* 0.125 * log2(e) */
#define SPLITS 4                  /* key splits in attention */

// ---------------------------------------------------------------------------
// 1. Convert the four 512x512 fp32 weight matrices to bf16 (concatenated).
// ---------------------------------------------------------------------------
__global__ __launch_bounds__(256) void convert_w(
    const float* __restrict__ wq, const float* __restrict__ wk,
    const float* __restrict__ wv, const float* __restrict__ wo,
    unsigned short* __restrict__ out)
{
    int i = blockIdx.x * 256 + threadIdx.x;
    const float* src = (i < 262144) ? wq : (i < 524288) ? wk : (i < 786432) ? wv : wo;
    out[i] = f2bf(src[i & 262143]);
}

// ---------------------------------------------------------------------------
// 2a. GroupNorm stats: grid (4 quarters, 64 b*g); partials -> part[(bg*4+q)*2]
// ---------------------------------------------------------------------------
__global__ __launch_bounds__(256) void gn_stats(
    const float* __restrict__ x, float* __restrict__ part)
{
    const int q = blockIdx.x, bg = blockIdx.y;
    const f4* xv = (const f4*)(x + (size_t)bg * 65536 + q * 16384);
    float s = 0.f, sq = 0.f;
    for (int i = threadIdx.x; i < 4096; i += 256) {
        f4 v = xv[i];
        s  += v.x + v.y + v.z + v.w;
        sq += v.x * v.x + v.y * v.y + v.z * v.z + v.w * v.w;
    }
    #pragma unroll
    for (int off = 32; off > 0; off >>= 1) {
        s  += __shfl_xor(s, off, 64);
        sq += __shfl_xor(sq, off, 64);
    }
    __shared__ float red[8];
    const int w = threadIdx.x >> 6, lane = threadIdx.x & 63;
    if (lane == 0) { red[w] = s; red[4 + w] = sq; }
    __syncthreads();
    if (threadIdx.x == 0) {
        part[(bg * 4 + q) * 2]     = red[0] + red[1] + red[2] + red[3];
        part[(bg * 4 + q) * 2 + 1] = red[4] + red[5] + red[6] + red[7];
    }
}

// ---------------------------------------------------------------------------
// 2b. GroupNorm apply -> h bf16 in [B*N, C] layout.
// ---------------------------------------------------------------------------
__global__ __launch_bounds__(256) void gn_apply(
    const float* __restrict__ x, const float* __restrict__ gamma,
    const float* __restrict__ beta, const float* __restrict__ part,
    unsigned short* __restrict__ h)
{
    const int q = blockIdx.x, bg = blockIdx.y;
    const int b = bg >> 5, g = bg & 31;
    float s = 0.f, sq = 0.f;
    #pragma unroll
    for (int j = 0; j < 4; ++j) {
        s  += part[(bg * 4 + j) * 2];
        sq += part[(bg * 4 + j) * 2 + 1];
    }
    const float mean = s * (1.f / 65536.f);
    const float rstd = rsqrtf(sq * (1.f / 65536.f) - mean * mean + 1e-5f);

    float gm[16], bt[16];
    #pragma unroll
    for (int c = 0; c < 16; ++c) {
        gm[c] = gamma[g * 16 + c] * rstd;
        bt[c] = beta[g * 16 + c];
    }
    const float* xg = x + (size_t)bg * 65536;
    const int n0 = q * 1024 + threadIdx.x * 4;
    float val[16][4];
    #pragma unroll
    for (int c = 0; c < 16; ++c) {
        f4 v = *(const f4*)&xg[(size_t)c * 4096 + n0];
        val[c][0] = (v.x - mean) * gm[c] + bt[c];
        val[c][1] = (v.y - mean) * gm[c] + bt[c];
        val[c][2] = (v.z - mean) * gm[c] + bt[c];
        val[c][3] = (v.w - mean) * gm[c] + bt[c];
    }
    #pragma unroll
    for (int nn = 0; nn < 4; ++nn) {
        ushort8 v0, v1;
        #pragma unroll
        for (int c = 0; c < 8; ++c)  v0[c]     = f2bf(val[c][nn]);
        #pragma unroll
        for (int c = 8; c < 16; ++c) v1[c - 8] = f2bf(val[c][nn]);
        unsigned short* dst = h + ((size_t)(b * 4096 + n0 + nn)) * 512 + g * 16;
        *(ushort8*)dst = v0;
        *(ushort8*)(dst + 8) = v1;
    }
}

// ---------------------------------------------------------------------------
// 3. bf16 GEMM  C[i,j] = sum_k A[i,k]*Bt[j,k] (+bias, +epilogue)
//    MODE 0: fused QKV. cols<1024 (Q,K) -> bf16 [i*1024+j] (Q pre-scaled by CS);
//            cols>=1024 (V) -> written ONLY to vt[bh][d][n] (fused transpose).
//    MODE 1: out fp32 transposed to [B,C,H,W] with residual, bias by i.
// ---------------------------------------------------------------------------
template <int MODE>
__global__ __launch_bounds__(256, 2) void gemm_bt(
    const unsigned short* __restrict__ A,   // [M,K] bf16
    const unsigned short* __restrict__ Bt,  // [N,K] bf16
    const float* __restrict__ bias0,
    const float* __restrict__ bias1,
    const float* __restrict__ bias2,
    const float* __restrict__ resid,
    void* __restrict__ outp,
    unsigned short* __restrict__ vtout,
    int M, int N, int K)
{
    __shared__ __attribute__((aligned(16))) unsigned short As[128 * 32];
    __shared__ __attribute__((aligned(16))) unsigned short Bs[128 * 32];
    const int t = threadIdx.x;
    const int w = t >> 6, lane = t & 63;
    const int l15 = lane & 15, l4 = lane >> 4;
    const int bm = blockIdx.y, bn = blockIdx.x;
    const int wm = (w >> 1) * 64, wn = (w & 1) * 64;

    f32x4 acc[4][4] = {};

    const int srow = t >> 2;
    const int sc8  = (t & 3) * 8;

    const unsigned short* gA0 = A  + (size_t)(bm * 128 + srow) * K + sc8;
    const unsigned short* gA1 = gA0 + (size_t)64 * K;
    const unsigned short* gB0 = Bt + (size_t)(bn * 128 + srow) * K + sc8;
    const unsigned short* gB1 = gB0 + (size_t)64 * K;
    unsigned short* lA0 = &As[w * 512];
    unsigned short* lA1 = &As[2048 + w * 512];
    unsigned short* lB0 = &Bs[w * 512];
    unsigned short* lB1 = &Bs[2048 + w * 512];

    for (int k0 = 0; k0 < K; k0 += 32) {
        __syncthreads();
        GLL(gA0 + k0, lA0);
        GLL(gA1 + k0, lA1);
        GLL(gB0 + k0, lB0);
        GLL(gB1 + k0, lB1);
        __syncthreads();

        bf16x8 af[4], bfr[4];
        #pragma unroll
        for (int mt = 0; mt < 4; ++mt)
            af[mt] = *(const bf16x8*)&As[(wm + mt * 16 + l15) * 32 + l4 * 8];
        #pragma unroll
        for (int nt = 0; nt < 4; ++nt)
            bfr[nt] = *(const bf16x8*)&Bs[(wn + nt * 16 + l15) * 32 + l4 * 8];
        #pragma unroll
        for (int mt = 0; mt < 4; ++mt)
            #pragma unroll
            for (int nt = 0; nt < 4; ++nt)
                acc[mt][nt] = __builtin_amdgcn_mfma_f32_16x16x32_bf16(
                    af[mt], bfr[nt], acc[mt][nt], 0, 0, 0);
    }

    if (MODE == 0) {
        unsigned short* outB = (unsigned short*)outp;
        #pragma unroll
        for (int nt = 0; nt < 4; ++nt) {
            int col = bn * 128 + wn + nt * 16 + l15;
            const float* bp = (col < 512) ? bias0 : (col < 1024) ? bias1 : bias2;
            float bv = bp[col & 511];
            if (col < 1024) {                    // Q (pre-scaled) / K -> qkv [8192][1024]
                float sc = (col < 512) ? CS : 1.0f;
                #pragma unroll
                for (int mt = 0; mt < 4; ++mt)
                    #pragma unroll
                    for (int r = 0; r < 4; ++r) {
                        int row = bm * 128 + wm + mt * 16 + l4 * 4 + r;
                        outB[(size_t)row * 1024 + col] = f2bf((acc[mt][nt][r] + bv) * sc);
                    }
            } else {                             // V -> vt[bh][d][n] directly
                int hd = col - 1024;             // h*64 + d
                #pragma unroll
                for (int mt = 0; mt < 4; ++mt) {
                    int m = bm * 128 + wm + mt * 16 + l4 * 4;   // n base (r=0)
                    int bb = m >> 12, n = m & 4095;
                    unsigned u0 = pk2bf(acc[mt][nt][0] + bv, acc[mt][nt][1] + bv);
                    unsigned u1 = pk2bf(acc[mt][nt][2] + bv, acc[mt][nt][3] + bv);
                    unsigned short* dst = vtout +
                        ((size_t)(bb * 8 + (hd >> 6)) * 64 + (hd & 63)) * 4096 + n;
                    *(u32x2*)dst = (u32x2){u0, u1};
                }
            }
        }
    } else {
        float* outF = (float*)outp;
        #pragma unroll
        for (int mt = 0; mt < 4; ++mt)
            #pragma unroll
            for (int nt = 0; nt < 4; ++nt)
                #pragma unroll
                for (int r = 0; r < 4; ++r) {
                    int c = bm * 128 + wm + mt * 16 + l4 * 4 + r;
                    int m = bn * 128 + wn + nt * 16 + l15;
                    int b = m >> 12, n = m & 4095;
                    size_t idx = ((size_t)(b * 512 + c)) * 4096 + n;
                    outF[idx] = acc[mt][nt][r] + bias0[c] + resid[idx];
                }
    }
}

// ---------------------------------------------------------------------------
// 4. Flash attention, 32x32x16 MFMA, 64 q/wave, fixed-shift softmax,
//    4-way key split. Block = 4 waves x 64 q = 256 q of one (b,h), 1024 keys.
//
//    Staging: GLL (global_load_lds) double-buffer, ONE barrier per tile
//    (T3 minimum-2-phase: __syncthreads' implicit vmcnt(0) drains the DMA).
//    LDS tile layout ("slice" form, GLL-lane-linear AND conflict-free reads):
//      K slice (kc*2+h5) at byte (kc*2+h5)*1024; row k at +k*16
//        holds K[k][kc*16+h5*8 .. +8)
//      V slice (kk*2+h5) at byte 8192+(kk*2+h5)*1024; row d at +d*16
//        holds Vt[d][kk*16+h5*8 .. +8)
//    Fragment reads are base + lane*16 (contiguous) -> zero bank conflicts;
//    the per-lane GLL *global* source is permuted to match (m173 pattern):
//    wave w stages slices 2w/2w+1 (cols w*16..+16 of all 64 rows).
//    ALL GLLs use imm offset 0 (r4 NaN: nonzero offset corrupts the LDS-DMA
//    destination); the +16B chunk uses an explicit g+8 pointer instead.
//
//    qt-split softmax order (QK0, sm0, QK1, sm1, PV) caps peak St liveness
//    at 32 regs -> ~160 total incl. 64 acc; __launch_bounds__(256,3).
//    (r1 lesson: cap must exceed true state; r3 lesson: acc counts too.)
//    Emits UNNORMALIZED bf16 O-partials + fp32 l-partials; combine_o merges.
// ---------------------------------------------------------------------------
__global__ __launch_bounds__(256, 3) void attn_kernel(
    const unsigned short* __restrict__ qkv, const unsigned short* __restrict__ vt,
    unsigned short* __restrict__ opart, float* __restrict__ lbuf)
{
    // 2 x 16 KB double buffer (K 8KB + V 8KB each); epilogue overlays all.
    __shared__ __attribute__((aligned(16))) unsigned short Sh[16384];
    char* ShB = (char*)Sh;

    const int bh = blockIdx.y, b = bh >> 3, h = bh & 7;
    const int qbase = blockIdx.x * 256;
    const int s = blockIdx.z, ks0 = s * 1024;
    const int t = threadIdx.x, w = t >> 6, lane = t & 63;
    const int l31 = lane & 31, h5 = lane >> 5;

    const unsigned short* Qg = qkv + ((size_t)(b * 4096 + qbase + w * 64)) * 1024 + h * 64;
    const unsigned short* Kg = qkv + ((size_t)(b * 4096 + ks0)) * 1024 + 512 + h * 64;
    const unsigned short* Vg = vt + ((size_t)bh) * 64 * 4096 + ks0;

    // Q fragments (B-operand, persistent): q=qt*32+l31, d=kc*16+h5*8+j
    bf16x8 qf[2][4];
    #pragma unroll
    for (int qt = 0; qt < 2; ++qt)
        #pragma unroll
        for (int kc = 0; kc < 4; ++kc)
            qf[qt][kc] = *(const bf16x8*)(Qg + (size_t)(qt * 32 + l31) * 1024 + kc * 16 + h5 * 8);

    f32x16 Oacc[2][2] = {};      // [dt][qt], C-layout: col=q, row=d
    float li[2] = {0.f, 0.f};

    // per-lane pre-permuted global sources (wave w stages slices 2w, 2w+1):
    //   j=0: rows=lane, cols w*16..+8 ; j=1: cols w*16+8..+16
    const unsigned short* gK0 = Kg + (size_t)lane * 1024 + w * 16;
    const unsigned short* gK1 = gK0 + 8;
    const unsigned short* gV0 = Vg + (size_t)lane * 4096 + w * 16;
    const unsigned short* gV1 = gV0 + 8;
    // wave-uniform LDS staging bases (bytes)
    const int lk = w * 2048;           // K slices 2w, 2w+1 (2 x 1KB)
    const int lv = 8192 + w * 2048;    // V slices

    // per-lane read base (bytes): h5*1024 + l31*16
    const int rbase = h5 * 1024 + l31 * 16;

    // prologue: stage tile 0 into buf 0
    GLL(gK0, ShB + lk);
    GLL(gK1, ShB + lk + 1024);
    GLL(gV0, ShB + lv);
    GLL(gV1, ShB + lv + 1024);
    __syncthreads();

    int cur = 0;
    for (int kt = 0; kt < 16; ++kt) {
        // stage next tile into buf^1 (async under this tile's compute)
        if (kt < 15) {
            const size_t ko = (size_t)(kt + 1) * 65536;   // 64 rows x 1024
            const int    vo = (kt + 1) * 64;              // 64 cols
            char* nb = ShB + (cur ^ 1) * 16384;
            GLL(gK0 + ko, nb + lk);
            GLL(gK1 + ko, nb + lk + 1024);
            GLL(gV0 + vo, nb + lv);
            GLL(gV1 + vo, nb + lv + 1024);
        }

        const char* Kr = ShB + cur * 16384 + rbase;
        const char* Vr = Kr + 8192;

        // ---- per qt: S^T = K @ Q(qt)^T ; exp2; row-sum; pack ----
        union PU { unsigned u[4]; bf16x8 v; };
        PU pf[2][4];
        #pragma unroll
        for (int qt = 0; qt < 2; ++qt) {
            f32x16 St[2] = {};
            #pragma unroll
            for (int ct = 0; ct < 2; ++ct)
                #pragma unroll
                for (int kc = 0; kc < 4; ++kc) {
                    bf16x8 kf = *(const bf16x8*)(Kr + kc * 2048 + ct * 512);
                    St[ct] = __builtin_amdgcn_mfma_f32_32x32x16_bf16(
                        kf, qf[qt][kc], St[ct], 0, 0, 0);
                }
            #pragma unroll
            for (int ct = 0; ct < 2; ++ct) {
                #pragma unroll
                for (int r = 0; r < 16; ++r)
                    St[ct][r] = EXP2(St[ct][r]);
                li[qt] += ((St[ct][0] + St[ct][1]) + (St[ct][2] + St[ct][3]))
                        + ((St[ct][4] + St[ct][5]) + (St[ct][6] + St[ct][7]))
                        + ((St[ct][8] + St[ct][9]) + (St[ct][10] + St[ct][11]))
                        + ((St[ct][12] + St[ct][13]) + (St[ct][14] + St[ct][15]));

                unsigned pk0 = pk2bf(St[ct][0],  St[ct][1]);
                unsigned pk1 = pk2bf(St[ct][2],  St[ct][3]);
                unsigned pk2 = pk2bf(St[ct][4],  St[ct][5]);
                unsigned pk3 = pk2bf(St[ct][6],  St[ct][7]);
                unsigned pk4 = pk2bf(St[ct][8],  St[ct][9]);
                unsigned pk5 = pk2bf(St[ct][10], St[ct][11]);
                unsigned pk6 = pk2bf(St[ct][12], St[ct][13]);
                unsigned pk7 = pk2bf(St[ct][14], St[ct][15]);
                pl32swap(pk0, pk2); pl32swap(pk1, pk3);
                pl32swap(pk4, pk6); pl32swap(pk5, pk7);
                pf[qt][ct * 2].u[0] = pk0; pf[qt][ct * 2].u[1] = pk1;
                pf[qt][ct * 2].u[2] = pk2; pf[qt][ct * 2].u[3] = pk3;
                pf[qt][ct * 2 + 1].u[0] = pk4; pf[qt][ct * 2 + 1].u[1] = pk5;
                pf[qt][ct * 2 + 1].u[2] = pk6; pf[qt][ct * 2 + 1].u[3] = pk7;
            }
        }

        // ---- O^T += V^T(dt) @ P^T(kk) ----
        #pragma unroll
        for (int kk = 0; kk < 4; ++kk)
            #pragma unroll
            for (int dt = 0; dt < 2; ++dt) {
                bf16x8 vf = *(const bf16x8*)(Vr + kk * 2048 + dt * 512);
                Oacc[dt][0] = __builtin_amdgcn_mfma_f32_32x32x16_bf16(vf, pf[0][kk].v, Oacc[dt][0], 0, 0, 0);
                Oacc[dt][1] = __builtin_amdgcn_mfma_f32_32x32x16_bf16(vf, pf[1][kk].v, Oacc[dt][1], 0, 0, 0);
            }

        __syncthreads();   // drains this wave's GLLs (vmcnt 0) + tile handoff
        cur ^= 1;
    }

    // ---- epilogue: UNNORMALIZED partials. l -> lbuf, O -> opart (bf16) ----
    #pragma unroll
    for (int qt = 0; qt < 2; ++qt) {
        float lf = li[qt] + __shfl_xor(li[qt], 32, 64);
        if (h5 == 0)
            lbuf[((size_t)s * 16 + bh) * 4096 + qbase + w * 64 + qt * 32 + l31] = lf;
    }

    // per-wave 32x72 scratch slices overlay the (dead) K/V buffers
    unsigned short* Eb = Sh + w * (32 * 72);
    #pragma unroll
    for (int qt = 0; qt < 2; ++qt) {
        #pragma unroll
        for (int dt = 0; dt < 2; ++dt)
            #pragma unroll
            for (int p = 0; p < 8; ++p) {
                int d = dt * 32 + 2 * (p & 1) + 8 * (p >> 1) + 4 * h5;
                unsigned u = pk2bf(Oacc[dt][qt][2 * p], Oacc[dt][qt][2 * p + 1]);
                *(unsigned*)&Eb[l31 * 72 + d] = u;
            }
        // same-wave read-back, 16B stores of [q][64] rows (2 lanes per row)
        unsigned short* Og = opart +
            (((size_t)s * 16 + bh) * 4096 + qbase + w * 64 + qt * 32) * 64;
        #pragma unroll
        for (int i = 0; i < 4; ++i) {
            int c8 = h5 * 4 + i;
            ushort8 val = *(const ushort8*)&Eb[l31 * 72 + c8 * 8];
            *(ushort8*)(Og + (size_t)l31 * 64 + c8 * 8) = val;
        }
    }
}

// ---------------------------------------------------------------------------
// 5. Combine the four key-split partials: O = (sum O_s)/(sum l_s) -> [B*N, C]
// ---------------------------------------------------------------------------
__global__ __launch_bounds__(256) void combine_o(
    const unsigned short* __restrict__ opart, const float* __restrict__ lbuf,
    unsigned short* __restrict__ o)
{
    int gid = blockIdx.x * 256 + threadIdx.x;   // 524288 = 65536 rows x 8 chunks
    int row = gid >> 3, c8 = gid & 7;           // row = bh*4096 + q
    int bh = row >> 12, q = row & 4095;
    int b = bh >> 3, h = bh & 7;
    float l = 0.f;
    #pragma unroll
    for (int sp = 0; sp < SPLITS; ++sp)
        l += lbuf[(size_t)sp * 65536 + row];
    float inv = 1.f / l;
    float acc[8] = {};
    #pragma unroll
    for (int sp = 0; sp < SPLITS; ++sp) {
        ushort8 ov = *(const ushort8*)(opart +
            (size_t)sp * 65536 * 64 + (size_t)row * 64 + c8 * 8);
        #pragma unroll
        for (int i = 0; i < 8; ++i) acc[i] += bf2f(ov[i]);
    }
    ushort8 r;
    #pragma unroll
    for (int i = 0; i < 8; ++i) r[i] = f2bf(acc[i] * inv);
    *(ushort8*)(o + ((size_t)(b * 4096 + q)) * 512 + h * 64 + c8 * 8) = r;
}

// ---------------------------------------------------------------------------
// launch
// ---------------------------------------------------------------------------
extern "C" void kernel_launch(void* const* d_in, const int* in_sizes, int n_in,
                              void* d_out, int out_size, void* d_ws, size_t ws_size,
                              hipStream_t stream) {
    const float* x     = (const float*)d_in[0];
    const float* gamma = (const float*)d_in[1];
    const float* beta  = (const float*)d_in[2];
    const float* Wq    = (const float*)d_in[3];
    const float* bq    = (const float*)d_in[4];
    const float* Wk    = (const float*)d_in[5];
    const float* bk    = (const float*)d_in[6];
    const float* Wv    = (const float*)d_in[7];
    const float* bv    = (const float*)d_in[8];
    const float* Wo    = (const float*)d_in[9];
    const float* bo    = (const float*)d_in[10];
    float* out = (float*)d_out;

    char* ws = (char*)d_ws;
    const size_t MB = 1024 * 1024;
    // Lifetime-overlapped layout (peak 60 MiB):
    //   wb     @  0  (2 MiB)   convert_w .. gemm<1>
    //   gnpart @  2  (4 KiB)
    //   qkv    @  3  (16 MiB)  [8192][1024] Q|K   (gemm<0> .. attn);
    //                          first 8 MiB reused as O [8192][512] by combine
    //   vtb    @ 19  (8 MiB)   [bh][64][4096]     (gemm<0> .. attn)
    //   h      @ 27  (8 MiB)   gn_apply .. gemm<0>   (dead before attn)
    //   opart  @ 27  (32 MiB)  attn .. combine       (overlays h)
    //   lbuf   @ 59  (1 MiB)   attn .. combine
    unsigned short* wb     = (unsigned short*)(ws);
    float*          gnpart = (float*)(ws + 2 * MB);
    unsigned short* qkv    = (unsigned short*)(ws + 3 * MB);
    unsigned short* vtb    = (unsigned short*)(ws + 19 * MB);
    unsigned short* h      = (unsigned short*)(ws + 27 * MB);
    unsigned short* opart  = (unsigned short*)(ws + 27 * MB);
    float*          lbuf   = (float*)(ws + 59 * MB);
    unsigned short* obuf   = qkv;   // O overlays the dead Q/K region

    convert_w<<<dim3(4096), dim3(256), 0, stream>>>(Wq, Wk, Wv, Wo, wb);
    gn_stats<<<dim3(4, 64), dim3(256), 0, stream>>>(x, gnpart);
    gn_apply<<<dim3(4, 64), dim3(256), 0, stream>>>(x, gamma, beta, gnpart, h);

    // fused qkv = h @ [Wq;Wk;Wv]^T + b; Q/K -> qkv (stride 1024), V -> vtb
    gemm_bt<0><<<dim3(12, 64), dim3(256), 0, stream>>>(
        h, wb, bq, bk, bv, nullptr, qkv, vtb, 8192, 1536, 512);

    attn_kernel<<<dim3(16, 16, SPLITS), dim3(256), 0, stream>>>(qkv, vtb, opart, lbuf);
    combine_o<<<dim3(2048), dim3(256), 0, stream>>>(opart, lbuf, obuf);

    // out[b,c,n] = x + (O @ Wo^T + bo)^T : C[c, m] with A=Wo, Bt=O
    gemm_bt<1><<<dim3(64, 4), dim3(256), 0, stream>>>(
        wb + 786432, obuf, bo, nullptr, nullptr, x, out, nullptr, 512, 8192, 512);
}

// Round 6
// 226.798 us; speedup vs baseline: 1.2926x; 1.2926x over previous
//
#include <hip/hip_runtime.h>
#include <cstdint>
#include <cstddef>

typedef __bf16 bf16x8 __attribute__((ext_vector_type(8)));
typedef float f32x2 __attribute__((ext_vector_type(2)));
typedef float f32x4 __attribute__((ext_vector_type(4)));
typedef float f32x16 __attribute__((ext_vector_type(16)));
typedef unsigned short ushort8 __attribute__((ext_vector_type(8)));
typedef unsigned u32x2 __attribute__((ext_vector_type(2)));
typedef float f4 __attribute__((ext_vector_type(4)));

__device__ __forceinline__ unsigned short f2bf(float f) {
    __bf16 b = (__bf16)f;
    return *(unsigned short*)&b;
}
__device__ __forceinline__ unsigned pk2bf(float a, float b) {
    __bf16 x = (__bf16)a, y = (__bf16)b;
    unsigned short ux = *(unsigned short*)&x, uy = *(unsigned short*)&y;
    return (unsigned)ux | ((unsigned)uy << 16);
}
__device__ __forceinline__ float bf2f(unsigned short u) {
    union { unsigned u; float f; } v; v.u = ((unsigned)u) << 16; return v.f;
}

#if __has_builtin(__builtin_amdgcn_exp2f)
#define EXP2(x) __builtin_amdgcn_exp2f(x)
#else
#define EXP2(x) exp2f(x)
#endif

// exchange high 32 lanes of x with low 32 lanes of y (v_permlane32_swap_b32)
__device__ __forceinline__ void pl32swap(unsigned& x, unsigned& y) {
#if __has_builtin(__builtin_amdgcn_permlane32_swap)
    auto r = __builtin_amdgcn_permlane32_swap(x, y, false, false);
    x = r[0]; y = r[1];
#else
    unsigned xs = (unsigned)__shfl_xor((int)x, 32, 64);
    unsigned ys = (unsigned)__shfl_xor((int)y, 32, 64);
    bool lo = ((threadIdx.x & 63) < 32);
    unsigned nx = lo ? x : ys;
    unsigned ny = lo ? xs : y;
    x = nx; y = ny;
#endif
}

// GLL only in gemm staging; offset=0 form only (r4: nonzero imm NaN'd).
#define GLL(g, l) __builtin_amdgcn_global_load_lds( \
    (__attribute__((address_space(1))) void*)(g), \
    (__attribute__((address_space(3))) void*)(l), 16, 0, 0)

#define CS 0.18033688011112042f   /* 0.125 * log2(e) */
#define SPLITS 2                  /* key splits in attention */

// ---------------------------------------------------------------------------
// 1. Convert the four 512x512 fp32 weight matrices to bf16 (concatenated).
// ---------------------------------------------------------------------------
__global__ __launch_bounds__(256) void convert_w(
    const float* __restrict__ wq, const float* __restrict__ wk,
    const float* __restrict__ wv, const float* __restrict__ wo,
    unsigned short* __restrict__ out)
{
    int i = blockIdx.x * 256 + threadIdx.x;
    const float* src = (i < 262144) ? wq : (i < 524288) ? wk : (i < 786432) ? wv : wo;
    out[i] = f2bf(src[i & 262143]);
}

// ---------------------------------------------------------------------------
// 2a. GroupNorm stats: grid (4 quarters, 64 b*g); partials -> part[(bg*4+q)*2]
// ---------------------------------------------------------------------------
__global__ __launch_bounds__(256) void gn_stats(
    const float* __restrict__ x, float* __restrict__ part)
{
    const int q = blockIdx.x, bg = blockIdx.y;
    const f4* xv = (const f4*)(x + (size_t)bg * 65536 + q * 16384);
    float s = 0.f, sq = 0.f;
    for (int i = threadIdx.x; i < 4096; i += 256) {
        f4 v = xv[i];
        s  += v.x + v.y + v.z + v.w;
        sq += v.x * v.x + v.y * v.y + v.z * v.z + v.w * v.w;
    }
    #pragma unroll
    for (int off = 32; off > 0; off >>= 1) {
        s  += __shfl_xor(s, off, 64);
        sq += __shfl_xor(sq, off, 64);
    }
    __shared__ float red[8];
    const int w = threadIdx.x >> 6, lane = threadIdx.x & 63;
    if (lane == 0) { red[w] = s; red[4 + w] = sq; }
    __syncthreads();
    if (threadIdx.x == 0) {
        part[(bg * 4 + q) * 2]     = red[0] + red[1] + red[2] + red[3];
        part[(bg * 4 + q) * 2 + 1] = red[4] + red[5] + red[6] + red[7];
    }
}

// ---------------------------------------------------------------------------
// 2b. GroupNorm apply -> h bf16 in [B*N, C] layout.
// ---------------------------------------------------------------------------
__global__ __launch_bounds__(256) void gn_apply(
    const float* __restrict__ x, const float* __restrict__ gamma,
    const float* __restrict__ beta, const float* __restrict__ part,
    unsigned short* __restrict__ h)
{
    const int q = blockIdx.x, bg = blockIdx.y;
    const int b = bg >> 5, g = bg & 31;
    float s = 0.f, sq = 0.f;
    #pragma unroll
    for (int j = 0; j < 4; ++j) {
        s  += part[(bg * 4 + j) * 2];
        sq += part[(bg * 4 + j) * 2 + 1];
    }
    const float mean = s * (1.f / 65536.f);
    const float rstd = rsqrtf(sq * (1.f / 65536.f) - mean * mean + 1e-5f);

    float gm[16], bt[16];
    #pragma unroll
    for (int c = 0; c < 16; ++c) {
        gm[c] = gamma[g * 16 + c] * rstd;
        bt[c] = beta[g * 16 + c];
    }
    const float* xg = x + (size_t)bg * 65536;
    const int n0 = q * 1024 + threadIdx.x * 4;
    float val[16][4];
    #pragma unroll
    for (int c = 0; c < 16; ++c) {
        f4 v = *(const f4*)&xg[(size_t)c * 4096 + n0];
        val[c][0] = (v.x - mean) * gm[c] + bt[c];
        val[c][1] = (v.y - mean) * gm[c] + bt[c];
        val[c][2] = (v.z - mean) * gm[c] + bt[c];
        val[c][3] = (v.w - mean) * gm[c] + bt[c];
    }
    #pragma unroll
    for (int nn = 0; nn < 4; ++nn) {
        ushort8 v0, v1;
        #pragma unroll
        for (int c = 0; c < 8; ++c)  v0[c]     = f2bf(val[c][nn]);
        #pragma unroll
        for (int c = 8; c < 16; ++c) v1[c - 8] = f2bf(val[c][nn]);
        unsigned short* dst = h + ((size_t)(b * 4096 + n0 + nn)) * 512 + g * 16;
        *(ushort8*)dst = v0;
        *(ushort8*)(dst + 8) = v1;
    }
}

// ---------------------------------------------------------------------------
// 3. bf16 GEMM  C[i,j] = sum_k A[i,k]*Bt[j,k] (+bias, +epilogue)
//    MODE 0: fused QKV. cols<1024 (Q,K) -> bf16 [i*1024+j] (Q pre-scaled by CS);
//            cols>=1024 (V) -> written ONLY to vt[bh][d][n] (fused transpose).
//    MODE 1: out fp32 transposed to [B,C,H,W] with residual, bias by i.
// ---------------------------------------------------------------------------
template <int MODE>
__global__ __launch_bounds__(256, 2) void gemm_bt(
    const unsigned short* __restrict__ A,   // [M,K] bf16
    const unsigned short* __restrict__ Bt,  // [N,K] bf16
    const float* __restrict__ bias0,
    const float* __restrict__ bias1,
    const float* __restrict__ bias2,
    const float* __restrict__ resid,
    void* __restrict__ outp,
    unsigned short* __restrict__ vtout,
    int M, int N, int K)
{
    __shared__ __attribute__((aligned(16))) unsigned short As[128 * 32];
    __shared__ __attribute__((aligned(16))) unsigned short Bs[128 * 32];
    const int t = threadIdx.x;
    const int w = t >> 6, lane = t & 63;
    const int l15 = lane & 15, l4 = lane >> 4;
    const int bm = blockIdx.y, bn = blockIdx.x;
    const int wm = (w >> 1) * 64, wn = (w & 1) * 64;

    f32x4 acc[4][4] = {};

    const int srow = t >> 2;
    const int sc8  = (t & 3) * 8;

    const unsigned short* gA0 = A  + (size_t)(bm * 128 + srow) * K + sc8;
    const unsigned short* gA1 = gA0 + (size_t)64 * K;
    const unsigned short* gB0 = Bt + (size_t)(bn * 128 + srow) * K + sc8;
    const unsigned short* gB1 = gB0 + (size_t)64 * K;
    unsigned short* lA0 = &As[w * 512];
    unsigned short* lA1 = &As[2048 + w * 512];
    unsigned short* lB0 = &Bs[w * 512];
    unsigned short* lB1 = &Bs[2048 + w * 512];

    for (int k0 = 0; k0 < K; k0 += 32) {
        __syncthreads();
        GLL(gA0 + k0, lA0);
        GLL(gA1 + k0, lA1);
        GLL(gB0 + k0, lB0);
        GLL(gB1 + k0, lB1);
        __syncthreads();

        bf16x8 af[4], bfr[4];
        #pragma unroll
        for (int mt = 0; mt < 4; ++mt)
            af[mt] = *(const bf16x8*)&As[(wm + mt * 16 + l15) * 32 + l4 * 8];
        #pragma unroll
        for (int nt = 0; nt < 4; ++nt)
            bfr[nt] = *(const bf16x8*)&Bs[(wn + nt * 16 + l15) * 32 + l4 * 8];
        #pragma unroll
        for (int mt = 0; mt < 4; ++mt)
            #pragma unroll
            for (int nt = 0; nt < 4; ++nt)
                acc[mt][nt] = __builtin_amdgcn_mfma_f32_16x16x32_bf16(
                    af[mt], bfr[nt], acc[mt][nt], 0, 0, 0);
    }

    if (MODE == 0) {
        unsigned short* outB = (unsigned short*)outp;
        #pragma unroll
        for (int nt = 0; nt < 4; ++nt) {
            int col = bn * 128 + wn + nt * 16 + l15;
            const float* bp = (col < 512) ? bias0 : (col < 1024) ? bias1 : bias2;
            float bv = bp[col & 511];
            if (col < 1024) {                    // Q (pre-scaled) / K -> qkv [8192][1024]
                float sc = (col < 512) ? CS : 1.0f;
                #pragma unroll
                for (int mt = 0; mt < 4; ++mt)
                    #pragma unroll
                    for (int r = 0; r < 4; ++r) {
                        int row = bm * 128 + wm + mt * 16 + l4 * 4 + r;
                        outB[(size_t)row * 1024 + col] = f2bf((acc[mt][nt][r] + bv) * sc);
                    }
            } else {                             // V -> vt[bh][d][n] directly
                int hd = col - 1024;             // h*64 + d
                #pragma unroll
                for (int mt = 0; mt < 4; ++mt) {
                    int m = bm * 128 + wm + mt * 16 + l4 * 4;   // n base (r=0)
                    int bb = m >> 12, n = m & 4095;
                    unsigned u0 = pk2bf(acc[mt][nt][0] + bv, acc[mt][nt][1] + bv);
                    unsigned u1 = pk2bf(acc[mt][nt][2] + bv, acc[mt][nt][3] + bv);
                    unsigned short* dst = vtout +
                        ((size_t)(bb * 8 + (hd >> 6)) * 64 + (hd & 63)) * 4096 + n;
                    *(u32x2*)dst = (u32x2){u0, u1};
                }
            }
        }
    } else {
        float* outF = (float*)outp;
        #pragma unroll
        for (int mt = 0; mt < 4; ++mt)
            #pragma unroll
            for (int nt = 0; nt < 4; ++nt)
                #pragma unroll
                for (int r = 0; r < 4; ++r) {
                    int c = bm * 128 + wm + mt * 16 + l4 * 4 + r;
                    int m = bn * 128 + wn + nt * 16 + l15;
                    int b = m >> 12, n = m & 4095;
                    size_t idx = ((size_t)(b * 512 + c)) * 4096 + n;
                    outF[idx] = acc[mt][nt][r] + bias0[c] + resid[idx];
                }
    }
}

// ---------------------------------------------------------------------------
// 4. Flash attention, 32x32x16 MFMA, 64 q/wave, fixed-shift softmax,
//    2-way key split. Block = 4 waves x 64 q = 256 q of one (b,h), 2048 keys.
//    r0 structure (reg-staged [64][72] tiles: coalesced global, minor bank
//    conflicts) + three additive changes:
//      (a) LDS double-buffer -> ONE barrier per tile: ds_write of tile kt+1
//          goes to buf^1 while compute reads buf[cur]; writes drain under
//          the MFMAs; the single end-of-tile barrier publishes them.
//      (b) s_setprio(1) around QK and PV MFMA clusters (T5, m191: +4-7%).
//      (c) packed f32x2 row-sums (v_pk_add_f32) halve the softmax adds.
//    launch_bounds stays (256,2): true per-wave state ~184 regs incl. 64
//    acc (r1/r3 lessons: forcing more waves spills; occupancy isn't the
//    limit anyway -- issue rate is).
//    Emits UNNORMALIZED bf16 O-partials + fp32 l-partials; combine_o merges.
// ---------------------------------------------------------------------------
__global__ __launch_bounds__(256, 2) void attn_kernel(
    const unsigned short* __restrict__ qkv, const unsigned short* __restrict__ vt,
    unsigned short* __restrict__ opart, float* __restrict__ lbuf)
{
    // 2 buffers x (K[64][72] + Vt[64][72]) ushorts = 36864 B total.
    // buf b: K at Sh + b*9216, V at Sh + b*9216 + 4608.
    // Epilogue overlays Sh[0..9216) (per-wave 32x72 slices).
    __shared__ __attribute__((aligned(16))) unsigned short Sh[2 * 9216];

    const int bh = blockIdx.y, b = bh >> 3, h = bh & 7;
    const int qbase = blockIdx.x * 256;
    const int s = blockIdx.z, ks0 = s * 2048;
    const int t = threadIdx.x, w = t >> 6, lane = t & 63;
    const int l31 = lane & 31, h5 = lane >> 5;

    const unsigned short* Qg = qkv + ((size_t)(b * 4096 + qbase + w * 64)) * 1024 + h * 64;
    const unsigned short* Kg = qkv + ((size_t)(b * 4096 + ks0)) * 1024 + 512 + h * 64;
    const unsigned short* Vg = vt + ((size_t)bh) * 64 * 4096 + ks0;

    // Q fragments (B-operand, persistent): q=qt*32+l31, d=kc*16+h5*8+j
    bf16x8 qf[2][4];
    #pragma unroll
    for (int qt = 0; qt < 2; ++qt)
        #pragma unroll
        for (int kc = 0; kc < 4; ++kc)
            qf[qt][kc] = *(const bf16x8*)(Qg + (size_t)(qt * 32 + l31) * 1024 + kc * 16 + h5 * 8);

    f32x16 Oacc[2][2] = {};      // [dt][qt], C-layout: col=q, row=d
    float li[2] = {0.f, 0.f};

    // staging: 256 threads x 32 B for each of K (8 KB) and V^T (8 KB)
    const int sr = t >> 2, sc = (t & 3) * 16;
    const unsigned short* gK = Kg + (size_t)sr * 1024 + sc;
    const unsigned short* gV = Vg + (size_t)sr * 4096 + sc;
    const int soff = sr * 72 + sc;     // within-buffer staging offset

    ushort8 kr[2], vr[2];
    // tile 0 -> regs -> buf0; then preload tile 1 into regs
    kr[0] = *(const ushort8*)(gK);
    kr[1] = *(const ushort8*)(gK + 8);
    vr[0] = *(const ushort8*)(gV);
    vr[1] = *(const ushort8*)(gV + 8);
    {
        unsigned short* dK = &Sh[soff];
        *(ushort8*)(dK)          = kr[0];
        *(ushort8*)(dK + 8)      = kr[1];
        *(ushort8*)(dK + 4608)     = vr[0];
        *(ushort8*)(dK + 4608 + 8) = vr[1];
    }
    kr[0] = *(const ushort8*)(gK + 65536);
    kr[1] = *(const ushort8*)(gK + 65536 + 8);
    vr[0] = *(const ushort8*)(gV + 64);
    vr[1] = *(const ushort8*)(gV + 64 + 8);
    __syncthreads();

    for (int kt = 0; kt < 32; ++kt) {
        const int cur = kt & 1;
        // (1) publish tile kt+1 into buf^1 (no barrier needed: its readers
        //     are all past the previous barrier; writes drain under compute)
        if (kt < 31) {
            unsigned short* dK = &Sh[(cur ^ 1) * 9216 + soff];
            *(ushort8*)(dK)          = kr[0];
            *(ushort8*)(dK + 8)      = kr[1];
            *(ushort8*)(dK + 4608)     = vr[0];
            *(ushort8*)(dK + 4608 + 8) = vr[1];
        }
        // (2) start fetching tile kt+2 from global (hides under this tile)
        if (kt < 30) {
            const unsigned short* nk = gK + (size_t)(kt + 2) * 65536;
            const unsigned short* nv = gV + (kt + 2) * 64;
            kr[0] = *(const ushort8*)(nk);
            kr[1] = *(const ushort8*)(nk + 8);
            vr[0] = *(const ushort8*)(nv);
            vr[1] = *(const ushort8*)(nv + 8);
        }

        const unsigned short* Ks  = &Sh[cur * 9216];
        const unsigned short* Vts = Ks + 4608;

        // ---- S^T tiles: St[qt][ct] = K(ct) @ Q(qt)^T (scale pre-folded) ----
        f32x16 St[2][2] = {};
        __builtin_amdgcn_s_setprio(1);
        #pragma unroll
        for (int ct = 0; ct < 2; ++ct)
            #pragma unroll
            for (int kc = 0; kc < 4; ++kc) {
                bf16x8 kf = *(const bf16x8*)&Ks[(ct * 32 + l31) * 72 + kc * 16 + h5 * 8];
                St[0][ct] = __builtin_amdgcn_mfma_f32_32x32x16_bf16(kf, qf[0][kc], St[0][ct], 0, 0, 0);
                St[1][ct] = __builtin_amdgcn_mfma_f32_32x32x16_bf16(kf, qf[1][kc], St[1][ct], 0, 0, 0);
            }
        __builtin_amdgcn_s_setprio(0);

        // ---- p = exp2(S'); packed row sums; pack to PV B-operand ----
        union PU { unsigned u[4]; bf16x8 v; };
        PU pf[2][4];
        #pragma unroll
        for (int qt = 0; qt < 2; ++qt) {
            #pragma unroll
            for (int ct = 0; ct < 2; ++ct)
                #pragma unroll
                for (int r = 0; r < 16; ++r)
                    St[qt][ct][r] = EXP2(St[qt][ct][r]);

            // packed pairwise sums (v_pk_add_f32)
            f32x2 ps = {0.f, 0.f};
            #pragma unroll
            for (int ct = 0; ct < 2; ++ct)
                #pragma unroll
                for (int r = 0; r < 16; r += 2) {
                    f32x2 e = {St[qt][ct][r], St[qt][ct][r + 1]};
                    ps += e;
                }
            li[qt] += ps[0] + ps[1];

            #pragma unroll
            for (int ct = 0; ct < 2; ++ct) {
                unsigned pk0 = pk2bf(St[qt][ct][0],  St[qt][ct][1]);
                unsigned pk1 = pk2bf(St[qt][ct][2],  St[qt][ct][3]);
                unsigned pk2 = pk2bf(St[qt][ct][4],  St[qt][ct][5]);
                unsigned pk3 = pk2bf(St[qt][ct][6],  St[qt][ct][7]);
                unsigned pk4 = pk2bf(St[qt][ct][8],  St[qt][ct][9]);
                unsigned pk5 = pk2bf(St[qt][ct][10], St[qt][ct][11]);
                unsigned pk6 = pk2bf(St[qt][ct][12], St[qt][ct][13]);
                unsigned pk7 = pk2bf(St[qt][ct][14], St[qt][ct][15]);
                pl32swap(pk0, pk2); pl32swap(pk1, pk3);
                pl32swap(pk4, pk6); pl32swap(pk5, pk7);
                pf[qt][ct * 2].u[0] = pk0; pf[qt][ct * 2].u[1] = pk1;
                pf[qt][ct * 2].u[2] = pk2; pf[qt][ct * 2].u[3] = pk3;
                pf[qt][ct * 2 + 1].u[0] = pk4; pf[qt][ct * 2 + 1].u[1] = pk5;
                pf[qt][ct * 2 + 1].u[2] = pk6; pf[qt][ct * 2 + 1].u[3] = pk7;
            }
        }

        // ---- O^T += V^T(dt) @ P^T(kk) ----
        __builtin_amdgcn_s_setprio(1);
        #pragma unroll
        for (int kk = 0; kk < 4; ++kk)
            #pragma unroll
            for (int dt = 0; dt < 2; ++dt) {
                bf16x8 vf = *(const bf16x8*)&Vts[(dt * 32 + l31) * 72 + kk * 16 + h5 * 8];
                Oacc[dt][0] = __builtin_amdgcn_mfma_f32_32x32x16_bf16(vf, pf[0][kk].v, Oacc[dt][0], 0, 0, 0);
                Oacc[dt][1] = __builtin_amdgcn_mfma_f32_32x32x16_bf16(vf, pf[1][kk].v, Oacc[dt][1], 0, 0, 0);
            }
        __builtin_amdgcn_s_setprio(0);

        __syncthreads();   // publish buf^1 writes; all reads of buf done
    }

    // ---- epilogue: UNNORMALIZED partials. l -> lbuf, O -> opart (bf16) ----
    #pragma unroll
    for (int qt = 0; qt < 2; ++qt) {
        float lf = li[qt] + __shfl_xor(li[qt], 32, 64);
        if (h5 == 0)
            lbuf[((size_t)s * 16 + bh) * 4096 + qbase + w * 64 + qt * 32 + l31] = lf;
    }

    // per-wave 32x72 scratch slices overlay the (dead) K/V buffers
    unsigned short* Eb = Sh + w * (32 * 72);
    #pragma unroll
    for (int qt = 0; qt < 2; ++qt) {
        #pragma unroll
        for (int dt = 0; dt < 2; ++dt)
            #pragma unroll
            for (int p = 0; p < 8; ++p) {
                int d = dt * 32 + 2 * (p & 1) + 8 * (p >> 1) + 4 * h5;
                unsigned u = pk2bf(Oacc[dt][qt][2 * p], Oacc[dt][qt][2 * p + 1]);
                *(unsigned*)&Eb[l31 * 72 + d] = u;
            }
        // same-wave read-back, 16B stores of [q][64] rows (2 lanes per row)
        unsigned short* Og = opart +
            (((size_t)s * 16 + bh) * 4096 + qbase + w * 64 + qt * 32) * 64;
        #pragma unroll
        for (int i = 0; i < 4; ++i) {
            int c8 = h5 * 4 + i;
            ushort8 val = *(const ushort8*)&Eb[l31 * 72 + c8 * 8];
            *(ushort8*)(Og + (size_t)l31 * 64 + c8 * 8) = val;
        }
    }
}

// ---------------------------------------------------------------------------
// 5. Combine the two key-split partials: O = (sum O_s)/(sum l_s) -> [B*N, C]
// ---------------------------------------------------------------------------
__global__ __launch_bounds__(256) void combine_o(
    const unsigned short* __restrict__ opart, const float* __restrict__ lbuf,
    unsigned short* __restrict__ o)
{
    int gid = blockIdx.x * 256 + threadIdx.x;   // 524288 = 65536 rows x 8 chunks
    int row = gid >> 3, c8 = gid & 7;           // row = bh*4096 + q
    int bh = row >> 12, q = row & 4095;
    int b = bh >> 3, h = bh & 7;
    float l = 0.f;
    #pragma unroll
    for (int sp = 0; sp < SPLITS; ++sp)
        l += lbuf[(size_t)sp * 65536 + row];
    float inv = 1.f / l;
    float acc[8] = {};
    #pragma unroll
    for (int sp = 0; sp < SPLITS; ++sp) {
        ushort8 ov = *(const ushort8*)(opart +
            (size_t)sp * 65536 * 64 + (size_t)row * 64 + c8 * 8);
        #pragma unroll
        for (int i = 0; i < 8; ++i) acc[i] += bf2f(ov[i]);
    }
    ushort8 r;
    #pragma unroll
    for (int i = 0; i < 8; ++i) r[i] = f2bf(acc[i] * inv);
    *(ushort8*)(o + ((size_t)(b * 4096 + q)) * 512 + h * 64 + c8 * 8) = r;
}

// ---------------------------------------------------------------------------
// launch
// ---------------------------------------------------------------------------
extern "C" void kernel_launch(void* const* d_in, const int* in_sizes, int n_in,
                              void* d_out, int out_size, void* d_ws, size_t ws_size,
                              hipStream_t stream) {
    const float* x     = (const float*)d_in[0];
    const float* gamma = (const float*)d_in[1];
    const float* beta  = (const float*)d_in[2];
    const float* Wq    = (const float*)d_in[3];
    const float* bq    = (const float*)d_in[4];
    const float* Wk    = (const float*)d_in[5];
    const float* bk    = (const float*)d_in[6];
    const float* Wv    = (const float*)d_in[7];
    const float* bv    = (const float*)d_in[8];
    const float* Wo    = (const float*)d_in[9];
    const float* bo    = (const float*)d_in[10];
    float* out = (float*)d_out;

    char* ws = (char*)d_ws;
    const size_t MB = 1024 * 1024;
    // Lifetime-overlapped layout (peak 60 MiB):
    //   wb     @  0  (2 MiB)   convert_w .. gemm<1>
    //   gnpart @  2  (4 KiB)
    //   qkv    @  3  (16 MiB)  [8192][1024] Q|K   (gemm<0> .. attn);
    //                          first 8 MiB reused as O [8192][512] by combine
    //   vtb    @ 19  (8 MiB)   [bh][64][4096]     (gemm<0> .. attn)
    //   h      @ 27  (8 MiB)   gn_apply .. gemm<0>   (dead before attn)
    //   opart  @ 27  (16 MiB)  attn .. combine       (overlays h)
    //   lbuf   @ 59  (512 KiB) attn .. combine
    unsigned short* wb     = (unsigned short*)(ws);
    float*          gnpart = (float*)(ws + 2 * MB);
    unsigned short* qkv    = (unsigned short*)(ws + 3 * MB);
    unsigned short* vtb    = (unsigned short*)(ws + 19 * MB);
    unsigned short* h      = (unsigned short*)(ws + 27 * MB);
    unsigned short* opart  = (unsigned short*)(ws + 27 * MB);
    float*          lbuf   = (float*)(ws + 59 * MB);
    unsigned short* obuf   = qkv;   // O overlays the dead Q/K region

    convert_w<<<dim3(4096), dim3(256), 0, stream>>>(Wq, Wk, Wv, Wo, wb);
    gn_stats<<<dim3(4, 64), dim3(256), 0, stream>>>(x, gnpart);
    gn_apply<<<dim3(4, 64), dim3(256), 0, stream>>>(x, gamma, beta, gnpart, h);

    // fused qkv = h @ [Wq;Wk;Wv]^T + b; Q/K -> qkv (stride 1024), V -> vtb
    gemm_bt<0><<<dim3(12, 64), dim3(256), 0, stream>>>(
        h, wb, bq, bk, bv, nullptr, qkv, vtb, 8192, 1536, 512);

    attn_kernel<<<dim3(16, 16, SPLITS), dim3(256), 0, stream>>>(qkv, vtb, opart, lbuf);
    combine_o<<<dim3(2048), dim3(256), 0, stream>>>(opart, lbuf, obuf);

    // out[b,c,n] = x + (O @ Wo^T + bo)^T : C[c, m] with A=Wo, Bt=O
    gemm_bt<1><<<dim3(64, 4), dim3(256), 0, stream>>>(
        wb + 786432, obuf, bo, nullptr, nullptr, x, out, nullptr, 512, 8192, 512);
}

// Round 7
// 223.722 us; speedup vs baseline: 1.3104x; 1.0137x over previous
//
#include <hip/hip_runtime.h>
#include <cstdint>
#include <cstddef>

typedef __bf16 bf16x8 __attribute__((ext_vector_type(8)));
typedef float f32x4 __attribute__((ext_vector_type(4)));
typedef float f32x16 __attribute__((ext_vector_type(16)));
typedef unsigned short ushort8 __attribute__((ext_vector_type(8)));
typedef unsigned u32x2 __attribute__((ext_vector_type(2)));
typedef float f4 __attribute__((ext_vector_type(4)));

__device__ __forceinline__ unsigned short f2bf(float f) {
    __bf16 b = (__bf16)f;
    return *(unsigned short*)&b;
}
__device__ __forceinline__ unsigned pk2bf(float a, float b) {
    __bf16 x = (__bf16)a, y = (__bf16)b;
    unsigned short ux = *(unsigned short*)&x, uy = *(unsigned short*)&y;
    return (unsigned)ux | ((unsigned)uy << 16);
}
__device__ __forceinline__ float bf2f(unsigned short u) {
    union { unsigned u; float f; } v; v.u = ((unsigned)u) << 16; return v.f;
}

#if __has_builtin(__builtin_amdgcn_exp2f)
#define EXP2(x) __builtin_amdgcn_exp2f(x)
#else
#define EXP2(x) exp2f(x)
#endif

// exchange high 32 lanes of x with low 32 lanes of y (v_permlane32_swap_b32)
__device__ __forceinline__ void pl32swap(unsigned& x, unsigned& y) {
#if __has_builtin(__builtin_amdgcn_permlane32_swap)
    auto r = __builtin_amdgcn_permlane32_swap(x, y, false, false);
    x = r[0]; y = r[1];
#else
    unsigned xs = (unsigned)__shfl_xor((int)x, 32, 64);
    unsigned ys = (unsigned)__shfl_xor((int)y, 32, 64);
    bool lo = ((threadIdx.x & 63) < 32);
    unsigned nx = lo ? x : ys;
    unsigned ny = lo ? xs : y;
    x = nx; y = ny;
#endif
}

// GLL only in gemm staging; offset=0 form only (r4: nonzero imm NaN'd).
#define GLL(g, l) __builtin_amdgcn_global_load_lds( \
    (__attribute__((address_space(1))) void*)(g), \
    (__attribute__((address_space(3))) void*)(l), 16, 0, 0)

#define CS 0.18033688011112042f   /* 0.125 * log2(e) */
#define SPLITS 2                  /* key splits in attention */

// ---------------------------------------------------------------------------
// 1. Convert the four 512x512 fp32 weight matrices to bf16 (concatenated).
// ---------------------------------------------------------------------------
__global__ __launch_bounds__(256) void convert_w(
    const float* __restrict__ wq, const float* __restrict__ wk,
    const float* __restrict__ wv, const float* __restrict__ wo,
    unsigned short* __restrict__ out)
{
    int i = blockIdx.x * 256 + threadIdx.x;
    const float* src = (i < 262144) ? wq : (i < 524288) ? wk : (i < 786432) ? wv : wo;
    out[i] = f2bf(src[i & 262143]);
}

// ---------------------------------------------------------------------------
// 2a. GroupNorm stats: grid (4 quarters, 64 b*g); partials -> part[(bg*4+q)*2]
// ---------------------------------------------------------------------------
__global__ __launch_bounds__(256) void gn_stats(
    const float* __restrict__ x, float* __restrict__ part)
{
    const int q = blockIdx.x, bg = blockIdx.y;
    const f4* xv = (const f4*)(x + (size_t)bg * 65536 + q * 16384);
    float s = 0.f, sq = 0.f;
    for (int i = threadIdx.x; i < 4096; i += 256) {
        f4 v = xv[i];
        s  += v.x + v.y + v.z + v.w;
        sq += v.x * v.x + v.y * v.y + v.z * v.z + v.w * v.w;
    }
    #pragma unroll
    for (int off = 32; off > 0; off >>= 1) {
        s  += __shfl_xor(s, off, 64);
        sq += __shfl_xor(sq, off, 64);
    }
    __shared__ float red[8];
    const int w = threadIdx.x >> 6, lane = threadIdx.x & 63;
    if (lane == 0) { red[w] = s; red[4 + w] = sq; }
    __syncthreads();
    if (threadIdx.x == 0) {
        part[(bg * 4 + q) * 2]     = red[0] + red[1] + red[2] + red[3];
        part[(bg * 4 + q) * 2 + 1] = red[4] + red[5] + red[6] + red[7];
    }
}

// ---------------------------------------------------------------------------
// 2b. GroupNorm apply -> h bf16 in [B*N, C] layout.
// ---------------------------------------------------------------------------
__global__ __launch_bounds__(256) void gn_apply(
    const float* __restrict__ x, const float* __restrict__ gamma,
    const float* __restrict__ beta, const float* __restrict__ part,
    unsigned short* __restrict__ h)
{
    const int q = blockIdx.x, bg = blockIdx.y;
    const int b = bg >> 5, g = bg & 31;
    float s = 0.f, sq = 0.f;
    #pragma unroll
    for (int j = 0; j < 4; ++j) {
        s  += part[(bg * 4 + j) * 2];
        sq += part[(bg * 4 + j) * 2 + 1];
    }
    const float mean = s * (1.f / 65536.f);
    const float rstd = rsqrtf(sq * (1.f / 65536.f) - mean * mean + 1e-5f);

    float gm[16], bt[16];
    #pragma unroll
    for (int c = 0; c < 16; ++c) {
        gm[c] = gamma[g * 16 + c] * rstd;
        bt[c] = beta[g * 16 + c];
    }
    const float* xg = x + (size_t)bg * 65536;
    const int n0 = q * 1024 + threadIdx.x * 4;
    float val[16][4];
    #pragma unroll
    for (int c = 0; c < 16; ++c) {
        f4 v = *(const f4*)&xg[(size_t)c * 4096 + n0];
        val[c][0] = (v.x - mean) * gm[c] + bt[c];
        val[c][1] = (v.y - mean) * gm[c] + bt[c];
        val[c][2] = (v.z - mean) * gm[c] + bt[c];
        val[c][3] = (v.w - mean) * gm[c] + bt[c];
    }
    #pragma unroll
    for (int nn = 0; nn < 4; ++nn) {
        ushort8 v0, v1;
        #pragma unroll
        for (int c = 0; c < 8; ++c)  v0[c]     = f2bf(val[c][nn]);
        #pragma unroll
        for (int c = 8; c < 16; ++c) v1[c - 8] = f2bf(val[c][nn]);
        unsigned short* dst = h + ((size_t)(b * 4096 + n0 + nn)) * 512 + g * 16;
        *(ushort8*)dst = v0;
        *(ushort8*)(dst + 8) = v1;
    }
}

// ---------------------------------------------------------------------------
// 3. bf16 GEMM  C[i,j] = sum_k A[i,k]*Bt[j,k] (+bias, +epilogue)
//    MODE 0: fused QKV. cols<1024 (Q,K) -> bf16 [i*1024+j] (Q pre-scaled by CS);
//            cols>=1024 (V) -> written ONLY to vt[bh][d][n] (fused transpose).
//    MODE 1: out fp32 transposed to [B,C,H,W] with residual, bias by i.
// ---------------------------------------------------------------------------
template <int MODE>
__global__ __launch_bounds__(256, 2) void gemm_bt(
    const unsigned short* __restrict__ A,   // [M,K] bf16
    const unsigned short* __restrict__ Bt,  // [N,K] bf16
    const float* __restrict__ bias0,
    const float* __restrict__ bias1,
    const float* __restrict__ bias2,
    const float* __restrict__ resid,
    void* __restrict__ outp,
    unsigned short* __restrict__ vtout,
    int M, int N, int K)
{
    __shared__ __attribute__((aligned(16))) unsigned short As[128 * 32];
    __shared__ __attribute__((aligned(16))) unsigned short Bs[128 * 32];
    const int t = threadIdx.x;
    const int w = t >> 6, lane = t & 63;
    const int l15 = lane & 15, l4 = lane >> 4;
    const int bm = blockIdx.y, bn = blockIdx.x;
    const int wm = (w >> 1) * 64, wn = (w & 1) * 64;

    f32x4 acc[4][4] = {};

    const int srow = t >> 2;
    const int sc8  = (t & 3) * 8;

    const unsigned short* gA0 = A  + (size_t)(bm * 128 + srow) * K + sc8;
    const unsigned short* gA1 = gA0 + (size_t)64 * K;
    const unsigned short* gB0 = Bt + (size_t)(bn * 128 + srow) * K + sc8;
    const unsigned short* gB1 = gB0 + (size_t)64 * K;
    unsigned short* lA0 = &As[w * 512];
    unsigned short* lA1 = &As[2048 + w * 512];
    unsigned short* lB0 = &Bs[w * 512];
    unsigned short* lB1 = &Bs[2048 + w * 512];

    for (int k0 = 0; k0 < K; k0 += 32) {
        __syncthreads();
        GLL(gA0 + k0, lA0);
        GLL(gA1 + k0, lA1);
        GLL(gB0 + k0, lB0);
        GLL(gB1 + k0, lB1);
        __syncthreads();

        bf16x8 af[4], bfr[4];
        #pragma unroll
        for (int mt = 0; mt < 4; ++mt)
            af[mt] = *(const bf16x8*)&As[(wm + mt * 16 + l15) * 32 + l4 * 8];
        #pragma unroll
        for (int nt = 0; nt < 4; ++nt)
            bfr[nt] = *(const bf16x8*)&Bs[(wn + nt * 16 + l15) * 32 + l4 * 8];
        #pragma unroll
        for (int mt = 0; mt < 4; ++mt)
            #pragma unroll
            for (int nt = 0; nt < 4; ++nt)
                acc[mt][nt] = __builtin_amdgcn_mfma_f32_16x16x32_bf16(
                    af[mt], bfr[nt], acc[mt][nt], 0, 0, 0);
    }

    if (MODE == 0) {
        unsigned short* outB = (unsigned short*)outp;
        #pragma unroll
        for (int nt = 0; nt < 4; ++nt) {
            int col = bn * 128 + wn + nt * 16 + l15;
            const float* bp = (col < 512) ? bias0 : (col < 1024) ? bias1 : bias2;
            float bv = bp[col & 511];
            if (col < 1024) {                    // Q (pre-scaled) / K -> qkv [8192][1024]
                float sc = (col < 512) ? CS : 1.0f;
                #pragma unroll
                for (int mt = 0; mt < 4; ++mt)
                    #pragma unroll
                    for (int r = 0; r < 4; ++r) {
                        int row = bm * 128 + wm + mt * 16 + l4 * 4 + r;
                        outB[(size_t)row * 1024 + col] = f2bf((acc[mt][nt][r] + bv) * sc);
                    }
            } else {                             // V -> vt[bh][d][n] directly
                int hd = col - 1024;             // h*64 + d
                #pragma unroll
                for (int mt = 0; mt < 4; ++mt) {
                    int m = bm * 128 + wm + mt * 16 + l4 * 4;   // n base (r=0)
                    int bb = m >> 12, n = m & 4095;
                    unsigned u0 = pk2bf(acc[mt][nt][0] + bv, acc[mt][nt][1] + bv);
                    unsigned u1 = pk2bf(acc[mt][nt][2] + bv, acc[mt][nt][3] + bv);
                    unsigned short* dst = vtout +
                        ((size_t)(bb * 8 + (hd >> 6)) * 64 + (hd & 63)) * 4096 + n;
                    *(u32x2*)dst = (u32x2){u0, u1};
                }
            }
        }
    } else {
        float* outF = (float*)outp;
        #pragma unroll
        for (int mt = 0; mt < 4; ++mt)
            #pragma unroll
            for (int nt = 0; nt < 4; ++nt)
                #pragma unroll
                for (int r = 0; r < 4; ++r) {
                    int c = bm * 128 + wm + mt * 16 + l4 * 4 + r;
                    int m = bn * 128 + wn + nt * 16 + l15;
                    int b = m >> 12, n = m & 4095;
                    size_t idx = ((size_t)(b * 512 + c)) * 4096 + n;
                    outF[idx] = acc[mt][nt][r] + bias0[c] + resid[idx];
                }
    }
}

// ---------------------------------------------------------------------------
// 4. Flash attention, 32x32x16 MFMA, 64 q/wave, fixed-shift softmax,
//    2-way key split. Block = 4 waves x 64 q = 256 q of one (b,h), 2048 keys.
//    THE r0 STRUCTURE (best measured: 84.7 us attn / 223.3 us total):
//    reg-staged [64][72] padded tiles (coalesced global reads, conflict-free
//    LDS reads), TWO barriers per tile, NO setprio (r6: setprio on lockstep
//    4-wave blocks regressed -10%), scalar row sums. Epilogue overlays the
//    dead K/V tiles (18.4 KB LDS total; occupancy-neutral at the 2-block
//    register cap: 116 arch + 64 acc ~ 180 regs -> 2 waves/SIMD).
//    Emits UNNORMALIZED bf16 O-partials + fp32 l-partials; combine_o merges.
// ---------------------------------------------------------------------------
__global__ __launch_bounds__(256, 2) void attn_kernel(
    const unsigned short* __restrict__ qkv, const unsigned short* __restrict__ vt,
    unsigned short* __restrict__ opart, float* __restrict__ lbuf)
{
    // [0 .. 64*72)       : K tile   (64 keys x 64 d, +8 pad)
    // [64*72 .. 2*64*72) : V^T tile (64 d x 64 keys, +8 pad)
    // epilogue: per-wave 32x72 scratch slices overlay the whole thing
    __shared__ __attribute__((aligned(16))) unsigned short Sh[2 * 64 * 72];
    unsigned short* KsB  = Sh;
    unsigned short* VtsB = Sh + 64 * 72;

    const int bh = blockIdx.y, b = bh >> 3, h = bh & 7;
    const int qbase = blockIdx.x * 256;
    const int s = blockIdx.z, ks0 = s * 2048;
    const int t = threadIdx.x, w = t >> 6, lane = t & 63;
    const int l31 = lane & 31, h5 = lane >> 5;

    const unsigned short* Qg = qkv + ((size_t)(b * 4096 + qbase + w * 64)) * 1024 + h * 64;
    const unsigned short* Kg = qkv + ((size_t)(b * 4096 + ks0)) * 1024 + 512 + h * 64;
    const unsigned short* Vg = vt + ((size_t)bh) * 64 * 4096 + ks0;

    // Q fragments (B-operand, persistent): q=qt*32+l31, d=kc*16+h5*8+j
    bf16x8 qf[2][4];
    #pragma unroll
    for (int qt = 0; qt < 2; ++qt)
        #pragma unroll
        for (int kc = 0; kc < 4; ++kc)
            qf[qt][kc] = *(const bf16x8*)(Qg + (size_t)(qt * 32 + l31) * 1024 + kc * 16 + h5 * 8);

    f32x16 Oacc[2][2] = {};      // [dt][qt], C-layout: col=q, row=d
    float li[2] = {0.f, 0.f};

    // staging: 256 threads x 32 B for each of K (8 KB) and V^T (8 KB)
    const int sr = t >> 2, sc = (t & 3) * 16;
    const unsigned short* gK = Kg + (size_t)sr * 1024 + sc;
    const unsigned short* gV = Vg + (size_t)sr * 4096 + sc;
    unsigned short* lK = KsB + sr * 72 + sc;
    unsigned short* lV = VtsB + sr * 72 + sc;

    ushort8 kr[2], vr[2];
    kr[0] = *(const ushort8*)(gK);
    kr[1] = *(const ushort8*)(gK + 8);
    vr[0] = *(const ushort8*)(gV);
    vr[1] = *(const ushort8*)(gV + 8);

    for (int kt = 0; kt < 32; ++kt) {
        __syncthreads();
        *(ushort8*)(lK)     = kr[0];
        *(ushort8*)(lK + 8) = kr[1];
        *(ushort8*)(lV)     = vr[0];
        *(ushort8*)(lV + 8) = vr[1];
        __syncthreads();
        if (kt < 31) {   // prefetch next tile into registers
            const unsigned short* nk = gK + (size_t)(kt + 1) * 65536;
            const unsigned short* nv = gV + (kt + 1) * 64;
            kr[0] = *(const ushort8*)(nk);
            kr[1] = *(const ushort8*)(nk + 8);
            vr[0] = *(const ushort8*)(nv);
            vr[1] = *(const ushort8*)(nv + 8);
        }

        // ---- S^T tiles: St[qt][ct] = K(ct) @ Q(qt)^T (scale pre-folded) ----
        f32x16 St[2][2] = {};
        #pragma unroll
        for (int ct = 0; ct < 2; ++ct)
            #pragma unroll
            for (int kc = 0; kc < 4; ++kc) {
                bf16x8 kf = *(const bf16x8*)(KsB + (ct * 32 + l31) * 72 + kc * 16 + h5 * 8);
                St[0][ct] = __builtin_amdgcn_mfma_f32_32x32x16_bf16(kf, qf[0][kc], St[0][ct], 0, 0, 0);
                St[1][ct] = __builtin_amdgcn_mfma_f32_32x32x16_bf16(kf, qf[1][kc], St[1][ct], 0, 0, 0);
            }

        // ---- p = exp2(S'); per-lane row sums; pack to PV B-operand ----
        union PU { unsigned u[4]; bf16x8 v; };
        PU pf[2][4];
        #pragma unroll
        for (int qt = 0; qt < 2; ++qt) {
            #pragma unroll
            for (int ct = 0; ct < 2; ++ct)
                #pragma unroll
                for (int r = 0; r < 16; ++r)
                    St[qt][ct][r] = EXP2(St[qt][ct][r]);
            float s0 = 0.f, s1 = 0.f;
            #pragma unroll
            for (int ct = 0; ct < 2; ++ct) {
                s0 += ((St[qt][ct][0] + St[qt][ct][1]) + (St[qt][ct][2] + St[qt][ct][3]))
                    + ((St[qt][ct][4] + St[qt][ct][5]) + (St[qt][ct][6] + St[qt][ct][7]));
                s1 += ((St[qt][ct][8] + St[qt][ct][9]) + (St[qt][ct][10] + St[qt][ct][11]))
                    + ((St[qt][ct][12] + St[qt][ct][13]) + (St[qt][ct][14] + St[qt][ct][15]));
            }
            li[qt] += s0 + s1;

            #pragma unroll
            for (int ct = 0; ct < 2; ++ct) {
                unsigned pk0 = pk2bf(St[qt][ct][0],  St[qt][ct][1]);
                unsigned pk1 = pk2bf(St[qt][ct][2],  St[qt][ct][3]);
                unsigned pk2 = pk2bf(St[qt][ct][4],  St[qt][ct][5]);
                unsigned pk3 = pk2bf(St[qt][ct][6],  St[qt][ct][7]);
                unsigned pk4 = pk2bf(St[qt][ct][8],  St[qt][ct][9]);
                unsigned pk5 = pk2bf(St[qt][ct][10], St[qt][ct][11]);
                unsigned pk6 = pk2bf(St[qt][ct][12], St[qt][ct][13]);
                unsigned pk7 = pk2bf(St[qt][ct][14], St[qt][ct][15]);
                pl32swap(pk0, pk2); pl32swap(pk1, pk3);
                pl32swap(pk4, pk6); pl32swap(pk5, pk7);
                pf[qt][ct * 2].u[0] = pk0; pf[qt][ct * 2].u[1] = pk1;
                pf[qt][ct * 2].u[2] = pk2; pf[qt][ct * 2].u[3] = pk3;
                pf[qt][ct * 2 + 1].u[0] = pk4; pf[qt][ct * 2 + 1].u[1] = pk5;
                pf[qt][ct * 2 + 1].u[2] = pk6; pf[qt][ct * 2 + 1].u[3] = pk7;
            }
        }

        // ---- O^T += V^T(dt) @ P^T(kk) ----
        #pragma unroll
        for (int kk = 0; kk < 4; ++kk)
            #pragma unroll
            for (int dt = 0; dt < 2; ++dt) {
                bf16x8 vf = *(const bf16x8*)(VtsB + (dt * 32 + l31) * 72 + kk * 16 + h5 * 8);
                Oacc[dt][0] = __builtin_amdgcn_mfma_f32_32x32x16_bf16(vf, pf[0][kk].v, Oacc[dt][0], 0, 0, 0);
                Oacc[dt][1] = __builtin_amdgcn_mfma_f32_32x32x16_bf16(vf, pf[1][kk].v, Oacc[dt][1], 0, 0, 0);
            }
    }

    // ---- epilogue: UNNORMALIZED partials. l -> lbuf, O -> opart (bf16) ----
    #pragma unroll
    for (int qt = 0; qt < 2; ++qt) {
        float lf = li[qt] + __shfl_xor(li[qt], 32, 64);
        if (h5 == 0)
            lbuf[((size_t)s * 16 + bh) * 4096 + qbase + w * 64 + qt * 32 + l31] = lf;
    }

    // all waves done reading K/V tiles -> overlay per-wave 32x72 scratch
    __syncthreads();
    unsigned short* Eb = Sh + w * (32 * 72);
    #pragma unroll
    for (int qt = 0; qt < 2; ++qt) {
        #pragma unroll
        for (int dt = 0; dt < 2; ++dt)
            #pragma unroll
            for (int p = 0; p < 8; ++p) {
                int d = dt * 32 + 2 * (p & 1) + 8 * (p >> 1) + 4 * h5;
                unsigned u = pk2bf(Oacc[dt][qt][2 * p], Oacc[dt][qt][2 * p + 1]);
                *(unsigned*)&Eb[l31 * 72 + d] = u;
            }
        // same-wave read-back, 16B stores of [q][64] rows (2 lanes per row)
        unsigned short* Og = opart +
            (((size_t)s * 16 + bh) * 4096 + qbase + w * 64 + qt * 32) * 64;
        #pragma unroll
        for (int i = 0; i < 4; ++i) {
            int c8 = h5 * 4 + i;
            ushort8 val = *(const ushort8*)&Eb[l31 * 72 + c8 * 8];
            *(ushort8*)(Og + (size_t)l31 * 64 + c8 * 8) = val;
        }
    }
}

// ---------------------------------------------------------------------------
// 5. Combine the two key-split partials: O = (sum O_s)/(sum l_s) -> [B*N, C]
// ---------------------------------------------------------------------------
__global__ __launch_bounds__(256) void combine_o(
    const unsigned short* __restrict__ opart, const float* __restrict__ lbuf,
    unsigned short* __restrict__ o)
{
    int gid = blockIdx.x * 256 + threadIdx.x;   // 524288 = 65536 rows x 8 chunks
    int row = gid >> 3, c8 = gid & 7;           // row = bh*4096 + q
    int bh = row >> 12, q = row & 4095;
    int b = bh >> 3, h = bh & 7;
    float l = 0.f;
    #pragma unroll
    for (int sp = 0; sp < SPLITS; ++sp)
        l += lbuf[(size_t)sp * 65536 + row];
    float inv = 1.f / l;
    float acc[8] = {};
    #pragma unroll
    for (int sp = 0; sp < SPLITS; ++sp) {
        ushort8 ov = *(const ushort8*)(opart +
            (size_t)sp * 65536 * 64 + (size_t)row * 64 + c8 * 8);
        #pragma unroll
        for (int i = 0; i < 8; ++i) acc[i] += bf2f(ov[i]);
    }
    ushort8 r;
    #pragma unroll
    for (int i = 0; i < 8; ++i) r[i] = f2bf(acc[i] * inv);
    *(ushort8*)(o + ((size_t)(b * 4096 + q)) * 512 + h * 64 + c8 * 8) = r;
}

// ---------------------------------------------------------------------------
// launch
// ---------------------------------------------------------------------------
extern "C" void kernel_launch(void* const* d_in, const int* in_sizes, int n_in,
                              void* d_out, int out_size, void* d_ws, size_t ws_size,
                              hipStream_t stream) {
    const float* x     = (const float*)d_in[0];
    const float* gamma = (const float*)d_in[1];
    const float* beta  = (const float*)d_in[2];
    const float* Wq    = (const float*)d_in[3];
    const float* bq    = (const float*)d_in[4];
    const float* Wk    = (const float*)d_in[5];
    const float* bk    = (const float*)d_in[6];
    const float* Wv    = (const float*)d_in[7];
    const float* bv    = (const float*)d_in[8];
    const float* Wo    = (const float*)d_in[9];
    const float* bo    = (const float*)d_in[10];
    float* out = (float*)d_out;

    char* ws = (char*)d_ws;
    const size_t MB = 1024 * 1024;
    // Lifetime-overlapped layout (peak 60 MiB):
    //   wb     @  0  (2 MiB)   convert_w .. gemm<1>
    //   gnpart @  2  (4 KiB)
    //   qkv    @  3  (16 MiB)  [8192][1024] Q|K   (gemm<0> .. attn);
    //                          first 8 MiB reused as O [8192][512] by combine
    //   vtb    @ 19  (8 MiB)   [bh][64][4096]     (gemm<0> .. attn)
    //   h      @ 27  (8 MiB)   gn_apply .. gemm<0>   (dead before attn)
    //   opart  @ 27  (16 MiB)  attn .. combine       (overlays h)
    //   lbuf   @ 59  (512 KiB) attn .. combine
    unsigned short* wb     = (unsigned short*)(ws);
    float*          gnpart = (float*)(ws + 2 * MB);
    unsigned short* qkv    = (unsigned short*)(ws + 3 * MB);
    unsigned short* vtb    = (unsigned short*)(ws + 19 * MB);
    unsigned short* h      = (unsigned short*)(ws + 27 * MB);
    unsigned short* opart  = (unsigned short*)(ws + 27 * MB);
    float*          lbuf   = (float*)(ws + 59 * MB);
    unsigned short* obuf   = qkv;   // O overlays the dead Q/K region

    convert_w<<<dim3(4096), dim3(256), 0, stream>>>(Wq, Wk, Wv, Wo, wb);
    gn_stats<<<dim3(4, 64), dim3(256), 0, stream>>>(x, gnpart);
    gn_apply<<<dim3(4, 64), dim3(256), 0, stream>>>(x, gamma, beta, gnpart, h);

    // fused qkv = h @ [Wq;Wk;Wv]^T + b; Q/K -> qkv (stride 1024), V -> vtb
    gemm_bt<0><<<dim3(12, 64), dim3(256), 0, stream>>>(
        h, wb, bq, bk, bv, nullptr, qkv, vtb, 8192, 1536, 512);

    attn_kernel<<<dim3(16, 16, SPLITS), dim3(256), 0, stream>>>(qkv, vtb, opart, lbuf);
    combine_o<<<dim3(2048), dim3(256), 0, stream>>>(opart, lbuf, obuf);

    // out[b,c,n] = x + (O @ Wo^T + bo)^T : C[c, m] with A=Wo, Bt=O
    gemm_bt<1><<<dim3(64, 4), dim3(256), 0, stream>>>(
        wb + 786432, obuf, bo, nullptr, nullptr, x, out, nullptr, 512, 8192, 512);
}

// Round 8
// 217.161 us; speedup vs baseline: 1.3499x; 1.0302x over previous
//
#include <hip/hip_runtime.h>
#include <cstdint>
#include <cstddef>

typedef __bf16 bf16x8 __attribute__((ext_vector_type(8)));
typedef float f32x4 __attribute__((ext_vector_type(4)));
typedef float f32x16 __attribute__((ext_vector_type(16)));
typedef unsigned short ushort8 __attribute__((ext_vector_type(8)));
typedef unsigned u32x2 __attribute__((ext_vector_type(2)));
typedef float f4 __attribute__((ext_vector_type(4)));

__device__ __forceinline__ unsigned short f2bf(float f) {
    __bf16 b = (__bf16)f;
    return *(unsigned short*)&b;
}
__device__ __forceinline__ unsigned pk2bf(float a, float b) {
    __bf16 x = (__bf16)a, y = (__bf16)b;
    unsigned short ux = *(unsigned short*)&x, uy = *(unsigned short*)&y;
    return (unsigned)ux | ((unsigned)uy << 16);
}
__device__ __forceinline__ float bf2f(unsigned short u) {
    union { unsigned u; float f; } v; v.u = ((unsigned)u) << 16; return v.f;
}

#if __has_builtin(__builtin_amdgcn_exp2f)
#define EXP2(x) __builtin_amdgcn_exp2f(x)
#else
#define EXP2(x) exp2f(x)
#endif

// exchange high 32 lanes of x with low 32 lanes of y (v_permlane32_swap_b32)
__device__ __forceinline__ void pl32swap(unsigned& x, unsigned& y) {
#if __has_builtin(__builtin_amdgcn_permlane32_swap)
    auto r = __builtin_amdgcn_permlane32_swap(x, y, false, false);
    x = r[0]; y = r[1];
#else
    unsigned xs = (unsigned)__shfl_xor((int)x, 32, 64);
    unsigned ys = (unsigned)__shfl_xor((int)y, 32, 64);
    bool lo = ((threadIdx.x & 63) < 32);
    unsigned nx = lo ? x : ys;
    unsigned ny = lo ? xs : y;
    x = nx; y = ny;
#endif
}

// GLL: offset=0 form only (r4: nonzero imm NaN'd on the LDS-DMA path).
#define GLL(g, l) __builtin_amdgcn_global_load_lds( \
    (__attribute__((address_space(1))) void*)(g), \
    (__attribute__((address_space(3))) void*)(l), 16, 0, 0)

#define CS 0.18033688011112042f   /* 0.125 * log2(e) */
#define SPLITS 2                  /* key splits in attention */

// ---------------------------------------------------------------------------
// 1. prep: blocks <4096 convert the four 512x512 fp32 weights to bf16;
//    blocks >=4096 compute GroupNorm partial stats (merged: saves a launch;
//    both depend only on kernel inputs, branch is block-uniform).
// ---------------------------------------------------------------------------
__global__ __launch_bounds__(256) void prep(
    const float* __restrict__ wq, const float* __restrict__ wk,
    const float* __restrict__ wv, const float* __restrict__ wo,
    unsigned short* __restrict__ wb,
    const float* __restrict__ x, float* __restrict__ part)
{
    const int bid = blockIdx.x;
    if (bid < 4096) {
        int i = bid * 256 + threadIdx.x;
        const float* src = (i < 262144) ? wq : (i < 524288) ? wk : (i < 786432) ? wv : wo;
        wb[i] = f2bf(src[i & 262143]);
        return;
    }
    // GroupNorm stats: blk = (bg*4 + q)
    const int blk = bid - 4096;
    const int q = blk & 3, bg = blk >> 2;
    const f4* xv = (const f4*)(x + (size_t)bg * 65536 + q * 16384);
    float s = 0.f, sq = 0.f;
    for (int i = threadIdx.x; i < 4096; i += 256) {
        f4 v = xv[i];
        s  += v.x + v.y + v.z + v.w;
        sq += v.x * v.x + v.y * v.y + v.z * v.z + v.w * v.w;
    }
    #pragma unroll
    for (int off = 32; off > 0; off >>= 1) {
        s  += __shfl_xor(s, off, 64);
        sq += __shfl_xor(sq, off, 64);
    }
    __shared__ float red[8];
    const int w = threadIdx.x >> 6, lane = threadIdx.x & 63;
    if (lane == 0) { red[w] = s; red[4 + w] = sq; }
    __syncthreads();
    if (threadIdx.x == 0) {
        part[(bg * 4 + q) * 2]     = red[0] + red[1] + red[2] + red[3];
        part[(bg * 4 + q) * 2 + 1] = red[4] + red[5] + red[6] + red[7];
    }
}

// ---------------------------------------------------------------------------
// 2. GroupNorm apply -> h bf16 in [B*N, C] layout.
// ---------------------------------------------------------------------------
__global__ __launch_bounds__(256) void gn_apply(
    const float* __restrict__ x, const float* __restrict__ gamma,
    const float* __restrict__ beta, const float* __restrict__ part,
    unsigned short* __restrict__ h)
{
    const int q = blockIdx.x, bg = blockIdx.y;
    const int b = bg >> 5, g = bg & 31;
    float s = 0.f, sq = 0.f;
    #pragma unroll
    for (int j = 0; j < 4; ++j) {
        s  += part[(bg * 4 + j) * 2];
        sq += part[(bg * 4 + j) * 2 + 1];
    }
    const float mean = s * (1.f / 65536.f);
    const float rstd = rsqrtf(sq * (1.f / 65536.f) - mean * mean + 1e-5f);

    float gm[16], bt[16];
    #pragma unroll
    for (int c = 0; c < 16; ++c) {
        gm[c] = gamma[g * 16 + c] * rstd;
        bt[c] = beta[g * 16 + c];
    }
    const float* xg = x + (size_t)bg * 65536;
    const int n0 = q * 1024 + threadIdx.x * 4;
    float val[16][4];
    #pragma unroll
    for (int c = 0; c < 16; ++c) {
        f4 v = *(const f4*)&xg[(size_t)c * 4096 + n0];
        val[c][0] = (v.x - mean) * gm[c] + bt[c];
        val[c][1] = (v.y - mean) * gm[c] + bt[c];
        val[c][2] = (v.z - mean) * gm[c] + bt[c];
        val[c][3] = (v.w - mean) * gm[c] + bt[c];
    }
    #pragma unroll
    for (int nn = 0; nn < 4; ++nn) {
        ushort8 v0, v1;
        #pragma unroll
        for (int c = 0; c < 8; ++c)  v0[c]     = f2bf(val[c][nn]);
        #pragma unroll
        for (int c = 8; c < 16; ++c) v1[c - 8] = f2bf(val[c][nn]);
        unsigned short* dst = h + ((size_t)(b * 4096 + n0 + nn)) * 512 + g * 16;
        *(ushort8*)dst = v0;
        *(ushort8*)(dst + 8) = v1;
    }
}

// ---------------------------------------------------------------------------
// 3. bf16 GEMM (QKV): C[i,j] = sum_k A[i,k]*Bt[j,k] + bias.
//    cols<1024 (Q,K) -> bf16 [i*1024+j] (Q pre-scaled by CS);
//    cols>=1024 (V) -> written ONLY to vt[bh][d][n] (fused transpose).
// ---------------------------------------------------------------------------
__global__ __launch_bounds__(256, 2) void gemm_qkv(
    const unsigned short* __restrict__ A,   // [M,K] bf16
    const unsigned short* __restrict__ Bt,  // [N,K] bf16
    const float* __restrict__ bias0,
    const float* __restrict__ bias1,
    const float* __restrict__ bias2,
    unsigned short* __restrict__ outB,
    unsigned short* __restrict__ vtout,
    int M, int N, int K)
{
    __shared__ __attribute__((aligned(16))) unsigned short As[128 * 32];
    __shared__ __attribute__((aligned(16))) unsigned short Bs[128 * 32];
    const int t = threadIdx.x;
    const int w = t >> 6, lane = t & 63;
    const int l15 = lane & 15, l4 = lane >> 4;
    const int bm = blockIdx.y, bn = blockIdx.x;
    const int wm = (w >> 1) * 64, wn = (w & 1) * 64;

    f32x4 acc[4][4] = {};

    const int srow = t >> 2;
    const int sc8  = (t & 3) * 8;

    const unsigned short* gA0 = A  + (size_t)(bm * 128 + srow) * K + sc8;
    const unsigned short* gA1 = gA0 + (size_t)64 * K;
    const unsigned short* gB0 = Bt + (size_t)(bn * 128 + srow) * K + sc8;
    const unsigned short* gB1 = gB0 + (size_t)64 * K;
    unsigned short* lA0 = &As[w * 512];
    unsigned short* lA1 = &As[2048 + w * 512];
    unsigned short* lB0 = &Bs[w * 512];
    unsigned short* lB1 = &Bs[2048 + w * 512];

    for (int k0 = 0; k0 < K; k0 += 32) {
        __syncthreads();
        GLL(gA0 + k0, lA0);
        GLL(gA1 + k0, lA1);
        GLL(gB0 + k0, lB0);
        GLL(gB1 + k0, lB1);
        __syncthreads();

        bf16x8 af[4], bfr[4];
        #pragma unroll
        for (int mt = 0; mt < 4; ++mt)
            af[mt] = *(const bf16x8*)&As[(wm + mt * 16 + l15) * 32 + l4 * 8];
        #pragma unroll
        for (int nt = 0; nt < 4; ++nt)
            bfr[nt] = *(const bf16x8*)&Bs[(wn + nt * 16 + l15) * 32 + l4 * 8];
        #pragma unroll
        for (int mt = 0; mt < 4; ++mt)
            #pragma unroll
            for (int nt = 0; nt < 4; ++nt)
                acc[mt][nt] = __builtin_amdgcn_mfma_f32_16x16x32_bf16(
                    af[mt], bfr[nt], acc[mt][nt], 0, 0, 0);
    }

    #pragma unroll
    for (int nt = 0; nt < 4; ++nt) {
        int col = bn * 128 + wn + nt * 16 + l15;
        const float* bp = (col < 512) ? bias0 : (col < 1024) ? bias1 : bias2;
        float bv = bp[col & 511];
        if (col < 1024) {                    // Q (pre-scaled) / K -> qkv [8192][1024]
            float sc = (col < 512) ? CS : 1.0f;
            #pragma unroll
            for (int mt = 0; mt < 4; ++mt)
                #pragma unroll
                for (int r = 0; r < 4; ++r) {
                    int row = bm * 128 + wm + mt * 16 + l4 * 4 + r;
                    outB[(size_t)row * 1024 + col] = f2bf((acc[mt][nt][r] + bv) * sc);
                }
        } else {                             // V -> vt[bh][d][n] directly
            int hd = col - 1024;             // h*64 + d
            #pragma unroll
            for (int mt = 0; mt < 4; ++mt) {
                int m = bm * 128 + wm + mt * 16 + l4 * 4;   // n base (r=0)
                int bb = m >> 12, n = m & 4095;
                unsigned u0 = pk2bf(acc[mt][nt][0] + bv, acc[mt][nt][1] + bv);
                unsigned u1 = pk2bf(acc[mt][nt][2] + bv, acc[mt][nt][3] + bv);
                unsigned short* dst = vtout +
                    ((size_t)(bb * 8 + (hd >> 6)) * 64 + (hd & 63)) * 4096 + n;
                *(u32x2*)dst = (u32x2){u0, u1};
            }
        }
    }
}

// ---------------------------------------------------------------------------
// 3b. Out-projection GEMM, 8-wave / 512-thread blocks.
//     C[c,m] = sum_k Wo[c,k]*O[m,k]; out fp32 [B,C,H,W] + bias + residual.
//     Grid (64,4) = 256 blocks = 1 block/CU, but 8 waves -> 2 waves/SIMD
//     (the old 4-wave version left the SIMDs at 1 wave each: zero latency
//     hiding). Wave grid 2x4; each wave computes 64x32; acc[4][2] = 32 regs.
//     Staging: 1 GLL per thread for each of A/B (512 x 16 B = 8 KB tile).
// ---------------------------------------------------------------------------
__global__ __launch_bounds__(512, 2) void gemm_out(
    const unsigned short* __restrict__ A,   // Wo bf16 [512][512]
    const unsigned short* __restrict__ Bt,  // O  bf16 [8192][512]
    const float* __restrict__ bias,
    const float* __restrict__ resid,
    float* __restrict__ outF)
{
    __shared__ __attribute__((aligned(16))) unsigned short As[128 * 32];
    __shared__ __attribute__((aligned(16))) unsigned short Bs[128 * 32];
    const int t = threadIdx.x;
    const int w = t >> 6, lane = t & 63;
    const int l15 = lane & 15, l4 = lane >> 4;
    const int bm = blockIdx.y, bn = blockIdx.x;
    const int wm = (w >> 2) * 64, wn = (w & 3) * 32;

    f32x4 acc[4][2] = {};

    // 512 threads stage a 128x32 tile: row = t>>2, col8 = (t&3)*8.
    // LDS index row*32 + col8 = t*8 -> dest addr = base + t*16B (lane-linear).
    const int srow = t >> 2, sc8 = (t & 3) * 8;
    const unsigned short* gA = A  + (size_t)(bm * 128 + srow) * 512 + sc8;
    const unsigned short* gB = Bt + (size_t)(bn * 128 + srow) * 512 + sc8;
    unsigned short* lA = &As[t * 8];
    unsigned short* lB = &Bs[t * 8];

    for (int k0 = 0; k0 < 512; k0 += 32) {
        __syncthreads();
        GLL(gA + k0, lA);
        GLL(gB + k0, lB);
        __syncthreads();

        bf16x8 af[4], bfr[2];
        #pragma unroll
        for (int mt = 0; mt < 4; ++mt)
            af[mt] = *(const bf16x8*)&As[(wm + mt * 16 + l15) * 32 + l4 * 8];
        #pragma unroll
        for (int nt = 0; nt < 2; ++nt)
            bfr[nt] = *(const bf16x8*)&Bs[(wn + nt * 16 + l15) * 32 + l4 * 8];
        #pragma unroll
        for (int mt = 0; mt < 4; ++mt)
            #pragma unroll
            for (int nt = 0; nt < 2; ++nt)
                acc[mt][nt] = __builtin_amdgcn_mfma_f32_16x16x32_bf16(
                    af[mt], bfr[nt], acc[mt][nt], 0, 0, 0);
    }

    #pragma unroll
    for (int mt = 0; mt < 4; ++mt)
        #pragma unroll
        for (int nt = 0; nt < 2; ++nt)
            #pragma unroll
            for (int r = 0; r < 4; ++r) {
                int c = bm * 128 + wm + mt * 16 + l4 * 4 + r;
                int m = bn * 128 + wn + nt * 16 + l15;
                int b = m >> 12, n = m & 4095;
                size_t idx = ((size_t)(b * 512 + c)) * 4096 + n;
                outF[idx] = acc[mt][nt][r] + bias[c] + resid[idx];
            }
}

// ---------------------------------------------------------------------------
// 4. Flash attention — the r0/r7 structure, UNCHANGED (best measured:
//    84.7-85.5 us). 32x32x16 MFMA, 64 q/wave, 2-way key split, reg-staged
//    [64][72] padded tiles, two barriers/tile, no setprio (r6: −10%),
//    scalar row sums, epilogue overlays the dead K/V tiles (18.4 KB LDS).
//    Plateau: MfmaUtil+VALUBusy ~86% = SIMD issue-port saturation at the
//    algorithm's VALU:MFMA mix, invariant across 2-3 blocks/CU (r0/r2/r3).
// ---------------------------------------------------------------------------
__global__ __launch_bounds__(256, 2) void attn_kernel(
    const unsigned short* __restrict__ qkv, const unsigned short* __restrict__ vt,
    unsigned short* __restrict__ opart, float* __restrict__ lbuf)
{
    __shared__ __attribute__((aligned(16))) unsigned short Sh[2 * 64 * 72];
    unsigned short* KsB  = Sh;
    unsigned short* VtsB = Sh + 64 * 72;

    const int bh = blockIdx.y, b = bh >> 3, h = bh & 7;
    const int qbase = blockIdx.x * 256;
    const int s = blockIdx.z, ks0 = s * 2048;
    const int t = threadIdx.x, w = t >> 6, lane = t & 63;
    const int l31 = lane & 31, h5 = lane >> 5;

    const unsigned short* Qg = qkv + ((size_t)(b * 4096 + qbase + w * 64)) * 1024 + h * 64;
    const unsigned short* Kg = qkv + ((size_t)(b * 4096 + ks0)) * 1024 + 512 + h * 64;
    const unsigned short* Vg = vt + ((size_t)bh) * 64 * 4096 + ks0;

    // Q fragments (B-operand, persistent): q=qt*32+l31, d=kc*16+h5*8+j
    bf16x8 qf[2][4];
    #pragma unroll
    for (int qt = 0; qt < 2; ++qt)
        #pragma unroll
        for (int kc = 0; kc < 4; ++kc)
            qf[qt][kc] = *(const bf16x8*)(Qg + (size_t)(qt * 32 + l31) * 1024 + kc * 16 + h5 * 8);

    f32x16 Oacc[2][2] = {};      // [dt][qt], C-layout: col=q, row=d
    float li[2] = {0.f, 0.f};

    // staging: 256 threads x 32 B for each of K (8 KB) and V^T (8 KB)
    const int sr = t >> 2, sc = (t & 3) * 16;
    const unsigned short* gK = Kg + (size_t)sr * 1024 + sc;
    const unsigned short* gV = Vg + (size_t)sr * 4096 + sc;
    unsigned short* lK = KsB + sr * 72 + sc;
    unsigned short* lV = VtsB + sr * 72 + sc;

    ushort8 kr[2], vr[2];
    kr[0] = *(const ushort8*)(gK);
    kr[1] = *(const ushort8*)(gK + 8);
    vr[0] = *(const ushort8*)(gV);
    vr[1] = *(const ushort8*)(gV + 8);

    for (int kt = 0; kt < 32; ++kt) {
        __syncthreads();
        *(ushort8*)(lK)     = kr[0];
        *(ushort8*)(lK + 8) = kr[1];
        *(ushort8*)(lV)     = vr[0];
        *(ushort8*)(lV + 8) = vr[1];
        __syncthreads();
        if (kt < 31) {   // prefetch next tile into registers
            const unsigned short* nk = gK + (size_t)(kt + 1) * 65536;
            const unsigned short* nv = gV + (kt + 1) * 64;
            kr[0] = *(const ushort8*)(nk);
            kr[1] = *(const ushort8*)(nk + 8);
            vr[0] = *(const ushort8*)(nv);
            vr[1] = *(const ushort8*)(nv + 8);
        }

        // ---- S^T tiles: St[qt][ct] = K(ct) @ Q(qt)^T (scale pre-folded) ----
        f32x16 St[2][2] = {};
        #pragma unroll
        for (int ct = 0; ct < 2; ++ct)
            #pragma unroll
            for (int kc = 0; kc < 4; ++kc) {
                bf16x8 kf = *(const bf16x8*)(KsB + (ct * 32 + l31) * 72 + kc * 16 + h5 * 8);
                St[0][ct] = __builtin_amdgcn_mfma_f32_32x32x16_bf16(kf, qf[0][kc], St[0][ct], 0, 0, 0);
                St[1][ct] = __builtin_amdgcn_mfma_f32_32x32x16_bf16(kf, qf[1][kc], St[1][ct], 0, 0, 0);
            }

        // ---- p = exp2(S'); per-lane row sums; pack to PV B-operand ----
        union PU { unsigned u[4]; bf16x8 v; };
        PU pf[2][4];
        #pragma unroll
        for (int qt = 0; qt < 2; ++qt) {
            #pragma unroll
            for (int ct = 0; ct < 2; ++ct)
                #pragma unroll
                for (int r = 0; r < 16; ++r)
                    St[qt][ct][r] = EXP2(St[qt][ct][r]);
            float s0 = 0.f, s1 = 0.f;
            #pragma unroll
            for (int ct = 0; ct < 2; ++ct) {
                s0 += ((St[qt][ct][0] + St[qt][ct][1]) + (St[qt][ct][2] + St[qt][ct][3]))
                    + ((St[qt][ct][4] + St[qt][ct][5]) + (St[qt][ct][6] + St[qt][ct][7]));
                s1 += ((St[qt][ct][8] + St[qt][ct][9]) + (St[qt][ct][10] + St[qt][ct][11]))
                    + ((St[qt][ct][12] + St[qt][ct][13]) + (St[qt][ct][14] + St[qt][ct][15]));
            }
            li[qt] += s0 + s1;

            #pragma unroll
            for (int ct = 0; ct < 2; ++ct) {
                unsigned pk0 = pk2bf(St[qt][ct][0],  St[qt][ct][1]);
                unsigned pk1 = pk2bf(St[qt][ct][2],  St[qt][ct][3]);
                unsigned pk2 = pk2bf(St[qt][ct][4],  St[qt][ct][5]);
                unsigned pk3 = pk2bf(St[qt][ct][6],  St[qt][ct][7]);
                unsigned pk4 = pk2bf(St[qt][ct][8],  St[qt][ct][9]);
                unsigned pk5 = pk2bf(St[qt][ct][10], St[qt][ct][11]);
                unsigned pk6 = pk2bf(St[qt][ct][12], St[qt][ct][13]);
                unsigned pk7 = pk2bf(St[qt][ct][14], St[qt][ct][15]);
                pl32swap(pk0, pk2); pl32swap(pk1, pk3);
                pl32swap(pk4, pk6); pl32swap(pk5, pk7);
                pf[qt][ct * 2].u[0] = pk0; pf[qt][ct * 2].u[1] = pk1;
                pf[qt][ct * 2].u[2] = pk2; pf[qt][ct * 2].u[3] = pk3;
                pf[qt][ct * 2 + 1].u[0] = pk4; pf[qt][ct * 2 + 1].u[1] = pk5;
                pf[qt][ct * 2 + 1].u[2] = pk6; pf[qt][ct * 2 + 1].u[3] = pk7;
            }
        }

        // ---- O^T += V^T(dt) @ P^T(kk) ----
        #pragma unroll
        for (int kk = 0; kk < 4; ++kk)
            #pragma unroll
            for (int dt = 0; dt < 2; ++dt) {
                bf16x8 vf = *(const bf16x8*)(VtsB + (dt * 32 + l31) * 72 + kk * 16 + h5 * 8);
                Oacc[dt][0] = __builtin_amdgcn_mfma_f32_32x32x16_bf16(vf, pf[0][kk].v, Oacc[dt][0], 0, 0, 0);
                Oacc[dt][1] = __builtin_amdgcn_mfma_f32_32x32x16_bf16(vf, pf[1][kk].v, Oacc[dt][1], 0, 0, 0);
            }
    }

    // ---- epilogue: UNNORMALIZED partials. l -> lbuf, O -> opart (bf16) ----
    #pragma unroll
    for (int qt = 0; qt < 2; ++qt) {
        float lf = li[qt] + __shfl_xor(li[qt], 32, 64);
        if (h5 == 0)
            lbuf[((size_t)s * 16 + bh) * 4096 + qbase + w * 64 + qt * 32 + l31] = lf;
    }

    // all waves done reading K/V tiles -> overlay per-wave 32x72 scratch
    __syncthreads();
    unsigned short* Eb = Sh + w * (32 * 72);
    #pragma unroll
    for (int qt = 0; qt < 2; ++qt) {
        #pragma unroll
        for (int dt = 0; dt < 2; ++dt)
            #pragma unroll
            for (int p = 0; p < 8; ++p) {
                int d = dt * 32 + 2 * (p & 1) + 8 * (p >> 1) + 4 * h5;
                unsigned u = pk2bf(Oacc[dt][qt][2 * p], Oacc[dt][qt][2 * p + 1]);
                *(unsigned*)&Eb[l31 * 72 + d] = u;
            }
        // same-wave read-back, 16B stores of [q][64] rows (2 lanes per row)
        unsigned short* Og = opart +
            (((size_t)s * 16 + bh) * 4096 + qbase + w * 64 + qt * 32) * 64;
        #pragma unroll
        for (int i = 0; i < 4; ++i) {
            int c8 = h5 * 4 + i;
            ushort8 val = *(const ushort8*)&Eb[l31 * 72 + c8 * 8];
            *(ushort8*)(Og + (size_t)l31 * 64 + c8 * 8) = val;
        }
    }
}

// ---------------------------------------------------------------------------
// 5. Combine the two key-split partials: O = (sum O_s)/(sum l_s) -> [B*N, C]
// ---------------------------------------------------------------------------
__global__ __launch_bounds__(256) void combine_o(
    const unsigned short* __restrict__ opart, const float* __restrict__ lbuf,
    unsigned short* __restrict__ o)
{
    int gid = blockIdx.x * 256 + threadIdx.x;   // 524288 = 65536 rows x 8 chunks
    int row = gid >> 3, c8 = gid & 7;           // row = bh*4096 + q
    int bh = row >> 12, q = row & 4095;
    int b = bh >> 3, h = bh & 7;
    float l = 0.f;
    #pragma unroll
    for (int sp = 0; sp < SPLITS; ++sp)
        l += lbuf[(size_t)sp * 65536 + row];
    float inv = 1.f / l;
    float acc[8] = {};
    #pragma unroll
    for (int sp = 0; sp < SPLITS; ++sp) {
        ushort8 ov = *(const ushort8*)(opart +
            (size_t)sp * 65536 * 64 + (size_t)row * 64 + c8 * 8);
        #pragma unroll
        for (int i = 0; i < 8; ++i) acc[i] += bf2f(ov[i]);
    }
    ushort8 r;
    #pragma unroll
    for (int i = 0; i < 8; ++i) r[i] = f2bf(acc[i] * inv);
    *(ushort8*)(o + ((size_t)(b * 4096 + q)) * 512 + h * 64 + c8 * 8) = r;
}

// ---------------------------------------------------------------------------
// launch
// ---------------------------------------------------------------------------
extern "C" void kernel_launch(void* const* d_in, const int* in_sizes, int n_in,
                              void* d_out, int out_size, void* d_ws, size_t ws_size,
                              hipStream_t stream) {
    const float* x     = (const float*)d_in[0];
    const float* gamma = (const float*)d_in[1];
    const float* beta  = (const float*)d_in[2];
    const float* Wq    = (const float*)d_in[3];
    const float* bq    = (const float*)d_in[4];
    const float* Wk    = (const float*)d_in[5];
    const float* bk    = (const float*)d_in[6];
    const float* Wv    = (const float*)d_in[7];
    const float* bv    = (const float*)d_in[8];
    const float* Wo    = (const float*)d_in[9];
    const float* bo    = (const float*)d_in[10];
    float* out = (float*)d_out;

    char* ws = (char*)d_ws;
    const size_t MB = 1024 * 1024;
    // Lifetime-overlapped layout (peak 60 MiB):
    //   wb     @  0  (2 MiB)   prep .. gemm_out
    //   gnpart @  2  (4 KiB)
    //   qkv    @  3  (16 MiB)  [8192][1024] Q|K   (gemm_qkv .. attn);
    //                          first 8 MiB reused as O [8192][512] by combine
    //   vtb    @ 19  (8 MiB)   [bh][64][4096]     (gemm_qkv .. attn)
    //   h      @ 27  (8 MiB)   gn_apply .. gemm_qkv  (dead before attn)
    //   opart  @ 27  (16 MiB)  attn .. combine       (overlays h)
    //   lbuf   @ 59  (512 KiB) attn .. combine
    unsigned short* wb     = (unsigned short*)(ws);
    float*          gnpart = (float*)(ws + 2 * MB);
    unsigned short* qkv    = (unsigned short*)(ws + 3 * MB);
    unsigned short* vtb    = (unsigned short*)(ws + 19 * MB);
    unsigned short* h      = (unsigned short*)(ws + 27 * MB);
    unsigned short* opart  = (unsigned short*)(ws + 27 * MB);
    float*          lbuf   = (float*)(ws + 59 * MB);
    unsigned short* obuf   = qkv;   // O overlays the dead Q/K region

    // weights->bf16 (4096 blocks) + GN stats (256 blocks) in one launch
    prep<<<dim3(4352), dim3(256), 0, stream>>>(Wq, Wk, Wv, Wo, wb, x, gnpart);
    gn_apply<<<dim3(4, 64), dim3(256), 0, stream>>>(x, gamma, beta, gnpart, h);

    // fused qkv = h @ [Wq;Wk;Wv]^T + b; Q/K -> qkv (stride 1024), V -> vtb
    gemm_qkv<<<dim3(12, 64), dim3(256), 0, stream>>>(
        h, wb, bq, bk, bv, qkv, vtb, 8192, 1536, 512);

    attn_kernel<<<dim3(16, 16, SPLITS), dim3(256), 0, stream>>>(qkv, vtb, opart, lbuf);
    combine_o<<<dim3(2048), dim3(256), 0, stream>>>(opart, lbuf, obuf);

    // out[b,c,n] = x + (O @ Wo^T + bo)^T : 8-wave blocks, 2 waves/SIMD
    gemm_out<<<dim3(64, 4), dim3(512), 0, stream>>>(
        wb + 786432, obuf, bo, x, out);
}